// Round 4
// baseline (25674.124 us; speedup 1.0000x reference)
//
#include <hip/hip_runtime.h>
#include <stdint.h>

#define DEV __device__ __forceinline__

namespace {

constexpr int kT = 512, kB = 32, kF = 128, kHE = 512, kHD = 512, kA = 256;

typedef _Float16 f16;
typedef _Float16 h4 __attribute__((ext_vector_type(4)));
typedef unsigned long long u64;

// ---- workspace layout (float-unit offsets) ----
constexpr size_t oWdecC  = 0;                          // f32 [2048][512] = Wih[:,512:]+Whh
constexpr size_t oWdWH   = oWdecC + 1048576;           // f16 [256][512]  = WdecW
constexpr size_t oEncSt  = oWdWH + 65536;              // f32 [32][512][512]
constexpr size_t oEncPr  = oEncSt + 8388608;           // f32 [32*512][256]
constexpr size_t oHseq   = oEncPr + 4194304;           // u64 [3][32][512] tagged decoder h
constexpr size_t oEbias  = oHseq + 98304;              // 2048
constexpr size_t oDbias  = oEbias + 2048;              // 2048
constexpr size_t oAb2    = oDbias + 2048;              // 256
constexpr size_t oCtr    = oAb2 + 256;                 // 2048 ints: [0]=abort,[16]=gate1,[17]=gate2
constexpr size_t oHenc   = oCtr + 2048;                // u64 [2][32][512] tagged encoder h
// aliased into encst (dead after dec gate1; tags zeroed between gates):
constexpr size_t aCtxP   = oEncSt;                     // u64 [3][32][16][512] ctx partials
constexpr size_t aScp    = aCtxP + 1572864;            // u64 [32][16][256]   dscore partials
constexpr size_t aCtxB   = aScp + 262144;              // u64 [3][32][512]    reduced ctx
constexpr size_t aDsp    = aCtxB + 98304;              // u64 [3][32][16]     denom partials
constexpr size_t aDen    = aDsp + 3072;                // u64 [3][32]         reduced denom

constexpr float kScale = 1.0f/64.0f;

DEV float frcp(float x){ return __builtin_amdgcn_rcpf(x); }
DEV float fsig(float x){ return frcp(1.f + __expf(-x)); }
DEV float ftanh(float x){ return 1.f - 2.f*frcp(__expf(2.f*x) + 1.f); }

DEV int   ld_ni(const int* p){ return __hip_atomic_load((int*)p, __ATOMIC_RELAXED, __HIP_MEMORY_SCOPE_AGENT); }
DEV void  st_ni(int* p, int v){ __hip_atomic_store(p, v, __ATOMIC_RELAXED, __HIP_MEMORY_SCOPE_AGENT); }
DEV u64   ld_nt(const u64* p){ return __hip_atomic_load((u64*)p, __ATOMIC_RELAXED, __HIP_MEMORY_SCOPE_AGENT); }
DEV void  st_nt(u64* p, u64 v){ __hip_atomic_store(p, v, __ATOMIC_RELAXED, __HIP_MEMORY_SCOPE_AGENT); }

DEV u64 pk(float v, int tag){ union{float f; uint32_t u;} c; c.f = v; return ((u64)(uint32_t)tag << 32) | (u64)c.u; }
DEV float payf(u64 x){ union{uint32_t u; float f;} c; c.u = (uint32_t)x; return c.f; }
DEV int   ptag(u64 x){ return (int)(x >> 32); }

// single-counter poll (one-time gates only)
DEV void wait_count(const int* p, int tgt, int* abortf){
  if (threadIdx.x < 64){
    int guard = 0;
    for (;;){
      if (ld_ni(p) >= tgt) break;
      if (ld_ni(abortf) != 0) break;
      if (++guard > (1<<21)){ st_ni(abortf, 1); break; }
      __builtin_amdgcn_s_sleep(2);
    }
  }
  __syncthreads();
}

} // namespace

// ================= kernel 1: init / weight packing =================
__global__ __launch_bounds__(256) void init_kernel(
    const float* __restrict__ eBih, const float* __restrict__ eBhh,
    const float* __restrict__ WdecW, const float* __restrict__ WdecB, const float* __restrict__ attnB,
    const float* __restrict__ dWih, const float* __restrict__ dWhh,
    const float* __restrict__ dBih, const float* __restrict__ dBhh,
    float* __restrict__ ws)
{
  float* whc = ws + oWdecC;            // fp32 [2048][512] = Wih[:,512:] + Whh
  f16* wdwh  = (f16*)(ws + oWdWH);
  u64* hseq  = (u64*)(ws + oHseq);
  u64* henc  = (u64*)(ws + oHenc);
  float* ebias = ws + oEbias;
  float* dbias = ws + oDbias;
  float* ab2w  = ws + oAb2;
  const int gid = blockIdx.x*256 + threadIdx.x;
  const int stride = gridDim.x*256;
  for (int i=gid; i<2048*512; i+=stride){
    int col = i>>9, k = i&511;
    whc[i] = dWih[((size_t)col<<10) + 512 + k] + dWhh[((size_t)col<<9) + k];
  }
  for (int i=gid; i<256*512; i+=stride)  wdwh[i] = (f16)WdecW[i];
  for (int i=gid; i<2048; i+=stride){ ebias[i] = eBih[i]+eBhh[i]; dbias[i] = dBih[i]+dBhh[i]; }
  for (int i=gid; i<256; i+=stride)  ab2w[i] = WdecB[i]+attnB[i];
  // encoder h: both buffers zero (value 0, tag 0)
  for (int i=gid; i<2*kB*kHE; i+=stride) henc[i] = 0ull;
  // decoder h: buffer 0 = initial h tagged 0; buffers 1,2 zero
  for (int i=gid; i<kB*kHD; i+=stride){
    int e = i & 511;
    float zi = dBih[e]+dBhh[e];
    float zg = dBih[1024+e]+dBhh[1024+e];
    float zo = dBih[1536+e]+dBhh[1536+e];
    float c0 = fsig(zi)*ftanh(zg);
    hseq[i] = pk(fsig(zo)*ftanh(c0), 0);
  }
  for (int i=gid; i<2*kB*kHD; i+=stride) hseq[kB*kHD + i] = 0ull;
}

// ================= kernel 2: encoder — tagged h exchange, no flags =================
__global__ __launch_bounds__(256, 1) void enc_kernel(
    const float* __restrict__ x, const float* __restrict__ eWih,
    const float* __restrict__ eWhh, float* __restrict__ ws)
{
  constexpr int WP = 644;
  constexpr int XP = 648;
  __shared__ float wsm[32*WP];
  __shared__ float xh[8*XP];
  __shared__ float zs[8][32];
  const float* ebias = ws + oEbias;
  float* encst = ws + oEncSt;
  u64* hq = (u64*)(ws + oHenc);
  int* ctr = (int*)(ws + oCtr);
  int* abortf = ctr;

  const int tid = threadIdx.x, bid = blockIdx.x;
  const int q = bid >> 6, j = bid & 63;    // b-group, e-slice
  const int b0 = q*8, e0 = j*8;

  for (int i = tid; i < 32*640; i += 256){
    int r = i / 640, k = i - r*640;
    int gate = r >> 3, el = r & 7;
    int grow = gate*kHE + e0 + el;
    float v = (k < kF) ? eWih[(size_t)grow*kF + k] : eWhh[(size_t)grow*kHE + (k - kF)];
    wsm[r*WP + k] = v;
  }
  const int b_l = tid >> 5, row = tid & 31;
  const float biasr = ebias[(row>>3)*kHE + e0 + (row&7)];
  const int b_p = tid >> 3, e_p = tid & 7;
  float creg = 0.f;
  __syncthreads();

  int p = 0;
  for (int t = 0; t < kT; ++t){
    __syncthreads();   // protect xh/zs reuse across iterations
    // stage x_t for 8 batches
    {
      int bl2 = tid >> 5, q4 = tid & 31;
      *(float4*)(&xh[bl2*XP + 4*q4]) = ((const float4*)(x + ((size_t)(b0+bl2)*kT + t)*kF))[q4];
    }
    // tagged h gather: 16 values/thread, poll until tags >= t
    {
      u64 gv[16];
      int guard = 0;
      for (;;){
        bool ok = true;
        #pragma unroll
        for (int i2=0;i2<16;++i2){
          int idx = tid + 256*i2; int bl2 = idx>>9, col = idx&511;
          gv[i2] = ld_nt(&hq[(size_t)p*kB*kHE + (size_t)(b0+bl2)*kHE + col]);
          ok &= (ptag(gv[i2]) >= t);
        }
        if (__all((int)ok)) break;
        if (ld_ni(abortf) != 0) break;
        if (++guard > (1<<20)){ st_ni(abortf, 1); break; }
      }
      #pragma unroll
      for (int i2=0;i2<16;++i2){
        int idx = tid + 256*i2; int bl2 = idx>>9, col = idx&511;
        xh[bl2*XP + kF + col] = payf(gv[i2]);
      }
    }
    __syncthreads();
    // dot: thread (b_l, row): z = w[row] . xh[b_l] over 640
    {
      const float4* wr = (const float4*)(&wsm[row*WP]);
      const float4* xr = (const float4*)(&xh[b_l*XP]);
      float a0=0.f, a1=0.f, a2=0.f, a3=0.f;
      #pragma unroll 8
      for (int kq = 0; kq < 160; ++kq){
        float4 w = wr[kq], v = xr[kq];
        a0 += w.x*v.x; a1 += w.y*v.y; a2 += w.z*v.z; a3 += w.w*v.w;
      }
      zs[b_l][row] = (a0+a1)+(a2+a3) + biasr;
    }
    __syncthreads();
    if (tid < 64){
      float zi = zs[b_p][0*8 + e_p];
      float zf = zs[b_p][1*8 + e_p];
      float zg = zs[b_p][2*8 + e_p];
      float zo = zs[b_p][3*8 + e_p];
      float c2 = fsig(zf)*creg + fsig(zi)*ftanh(zg);
      creg = c2;
      float h = fsig(zo)*ftanh(c2);
      int b = b0 + b_p, e = e0 + e_p;
      st_nt(&hq[(size_t)(p^1)*kB*kHE + (size_t)b*kHE + e], pk(h, t+1));
      encst[((size_t)b*kT + t)*kHE + e] = h;   // plain; published at kernel end
    }
    p ^= 1;
  }
}

// ================= kernel 3: enc_proj = enc_states @ Wenc^T + b =================
__global__ __launch_bounds__(256) void encproj_kernel(
    const float* __restrict__ WencW, const float* __restrict__ WencB,
    float* __restrict__ ws)
{
  const float* encst = ws + oEncSt;
  float* encpr = ws + oEncPr;
  __shared__ float4 et[32][32];
  const int tid = threadIdx.x, bid = blockIdx.x;
  const int r0 = bid*32;
  float acc[32];
  #pragma unroll
  for (int i=0;i<32;++i) acc[i]=0.f;
  for (int kt=0; kt<4; ++kt){
    #pragma unroll
    for (int i2=0;i2<4;++i2){
      int q = tid + i2*256;
      int row = q>>5, qi = q&31;
      et[row][qi] = ((const float4*)(encst + ((size_t)(r0+row))*kHE + kt*128))[qi];
    }
    __syncthreads();
    const float4* wv = (const float4*)(WencW + (size_t)tid*kHE + kt*128);
    #pragma unroll 1
    for (int q=0;q<32;++q){
      float4 w = wv[q];
      #pragma unroll
      for (int i=0;i<32;++i){
        float4 e4 = et[i][q];
        acc[i] += e4.x*w.x + e4.y*w.y + e4.z*w.z + e4.w*w.w;
      }
    }
    __syncthreads();
  }
  float bb = WencB[tid];
  #pragma unroll
  for (int i=0;i<32;++i) encpr[((size_t)(r0+i))*kA + tid] = acc[i] + bb;
}

// ================= kernel 4: decoder — tagged-payload sync, no flags/stamps =================
namespace {
struct SA  { float h[32]; float sc[256]; float lw[32]; };
struct SC  { float xt[16][260]; float zb[128][2]; };
struct __align__(16) SmemDec {
  float wsl[8][1028];      // fp32 weight slab: rows (gate*2+e_l), K=1024 (ctx|h)
  float v[256];
  union { SA a; SC c; } u;
};
}

__global__ __launch_bounds__(256, 2) void dec_kernel(
    const float* __restrict__ Vw, const float* __restrict__ dWih,
    float* __restrict__ out, float* __restrict__ ws)
{
  __shared__ SmemDec sm;
  const int tid = threadIdx.x, bid = blockIdx.x;
  const float* whc = ws + oWdecC;
  const f16* wdwh  = (const f16*)(ws + oWdWH);
  const float* encst = ws + oEncSt;
  const float* encpr = ws + oEncPr;
  u64* hseq = (u64*)(ws + oHseq);
  u64* ctxp = (u64*)(ws + aCtxP);
  u64* scp  = (u64*)(ws + aScp);
  u64* ctxb = (u64*)(ws + aCtxB);
  u64* dsp  = (u64*)(ws + aDsp);
  u64* den  = (u64*)(ws + aDen);
  const float* dbias = ws + oDbias;
  const float* ab2w  = ws + oAb2;
  int* ctr   = (int*)(ws + oCtr);
  int* abortf = ctr;
  int* gate1 = ctr + 16;
  int* gate2 = ctr + 17;

  const int bA = bid >> 4, tc = bid & 15, t0a = tc*32;      // A/B role
  const int half = bid >> 8, ecp = bid & 255, e0c = ecp*2;  // C role
  const bool isR = (tc == 0);
  const int col_l = tid & 127, ksC = tid >> 7;
  const int e_lC = col_l & 1, gateC = (col_l>>1)&3, b_lC = col_l>>3;
  const int wrow = gateC*2 + e_lC;

  // ---- one-time: weight slab (8 cols x 1024 K) -> LDS
  for (int i = tid; i < 8*1024; i += 256){
    int rr = i >> 10, k = i & 1023;
    int col = (rr>>1)*kHD + e0c + (rr&1);
    float v = (k < 512) ? dWih[(size_t)col*1024 + k] : whc[(size_t)col*512 + (k-512)];
    sm.wsl[rr][k] = v;
  }
  sm.v[tid] = Vw[tid];

  // ---- one-time register residents (step-invariant)
  h4 wA[8];
  { const h4* wv0 = (const h4*)(wdwh + (size_t)tid*kHD + t0a);
    #pragma unroll
    for (int q=0;q<8;++q) wA[q] = wv0[q]; }
  const int tl = tid>>3, as = tid&7;
  float4 eprR[8];
  { const float* eb2 = encpr + ((size_t)bA*kT + t0a + tl)*kA + as*4;
    #pragma unroll
    for (int q=0;q<8;++q) eprR[q] = *(const float4*)(eb2 + q*32); }
  float2 ev[32];                                   // encoder-state tile in regs
  { const float* eb = encst + ((size_t)bA*kT + t0a)*kHE + 2*tid;
    #pragma unroll
    for (int j=0;j<32;++j) ev[j] = *(const float2*)(eb + (size_t)j*kHE); }

  const float ab2r = ab2w[tid];
  float cregD=0, dbi=0, dbf=0, dbg=0, dbo=0;
  if (tid < 32){
    int e = e0c + (tid&1);
    dbi = dbias[e]; dbf = dbias[512+e]; dbg = dbias[1024+e]; dbo = dbias[1536+e];
    cregD = fsig(dbi)*ftanh(dbg);
  }
  // ---- gate1: every block's encst/encpr register loads complete before the alias is touched
  __syncthreads();
  if (tid == 0) atomicAdd(gate1, 1);
  wait_count(gate1, 512, abortf);
  // ---- zero tag words of aliased exchange buffers (own slices only)
  #pragma unroll
  for (int k=0;k<3;++k)
    for (int i=tid; i<512; i+=256) st_nt(&ctxp[(((size_t)k*kB + bA)*16 + tc)*512 + i], 0ull);
  st_nt(&scp[((size_t)bA*16 + tc)*256 + tid], 0ull);
  if (isR){
    #pragma unroll
    for (int k=0;k<3;++k)
      for (int i=tid; i<512; i+=256) st_nt(&ctxb[((size_t)k*kB + bA)*512 + i], 0ull);
    if (tid < 48){ int k = tid>>4, jj = tid&15; st_nt(&dsp[((size_t)k*kB + bA)*16 + jj], 0ull); }
    if (tid < 3)  st_nt(&den[(size_t)tid*kB + bA], 0ull);
  }
  __syncthreads();
  if (tid == 0) atomicAdd(gate2, 1);
  wait_count(gate2, 512, abortf);

  const int off  = (2*tid) & 255;
  const int mych = tid >> 7;

  int r = 0;
  for (int t=0; t<kT; ++t){
    const int rn = (r==2) ? 0 : r+1;
    __syncthreads();   // union SC (prev step) -> SA transition
    // ---- A: poll-gather h window (tags >= t), stage to LDS ----
    if (tid < 32){
      const u64* hp = hseq + ((size_t)r*kB + bA)*kHE + t0a + tid;
      u64 v; int guard = 0;
      for (;;){ v = ld_nt(hp); if (ptag(v) >= t) break;
                if (ld_ni(abortf) != 0) break;
                if (++guard > (1<<20)){ st_ni(abortf,1); break; } }
      sm.u.a.h[tid] = payf(v);
    }
    __syncthreads();
    {
      float sp = 0.f;
      #pragma unroll
      for (int q=0;q<8;++q){
        h4 w = wA[q];
        sp += (float)w.x*sm.u.a.h[q*4+0] + (float)w.y*sm.u.a.h[q*4+1]
            + (float)w.z*sm.u.a.h[q*4+2] + (float)w.w*sm.u.a.h[q*4+3];
      }
      st_nt(&scp[((size_t)bA*16 + tc)*256 + tid], pk(sp, t+1));   // no ack, no stamp
    }
    // ---- C-prep: poll-gather full h rows of this half (tags >= t) ----
    float hux[16], huy[16];
    {
      const u64* hb = hseq + ((size_t)r*kB + half*16)*kHE + 2*tid;
      u64 vx[16], vy[16];
      int guard = 0;
      for (;;){
        bool ok = true;
        #pragma unroll
        for (int b=0;b<16;++b){
          vx[b] = ld_nt(hb + (size_t)b*kHE);
          vy[b] = ld_nt(hb + (size_t)b*kHE + 1);
          ok &= (ptag(vx[b]) >= t) & (ptag(vy[b]) >= t);
        }
        if (__all((int)ok)) break;
        if (ld_ni(abortf) != 0) break;
        if (++guard > (1<<20)){ st_ni(abortf,1); break; }
      }
      #pragma unroll
      for (int b=0;b<16;++b){ hux[b] = payf(vx[b]); huy[b] = payf(vy[b]); }
    }
    // ---- B: poll-gather 16 dscore partials (tags >= t+1), logits, lw, ctx partial ----
    {
      const u64* sp2 = scp + (size_t)bA*16*256 + tid;
      u64 sv[16];
      int guard = 0;
      for (;;){
        bool ok = true;
        #pragma unroll
        for (int j=0;j<16;++j){ sv[j] = ld_nt(sp2 + (size_t)j*256); ok &= (ptag(sv[j]) >= t+1); }
        if (__all((int)ok)) break;
        if (ld_ni(abortf) != 0) break;
        if (++guard > (1<<20)){ st_ni(abortf,1); break; }
      }
      float sc = ab2r;
      #pragma unroll
      for (int j=0;j<16;++j) sc += payf(sv[j]);
      sm.u.a.sc[tid] = sc;
    }
    __syncthreads();
    {
      float acc = 0.f;
      #pragma unroll
      for (int q=0;q<8;++q){
        int a0 = q*32 + as*4;
        float4 e4 = eprR[q];
        acc += sm.v[a0+0]*ftanh(e4.x + sm.u.a.sc[a0+0]);
        acc += sm.v[a0+1]*ftanh(e4.y + sm.u.a.sc[a0+1]);
        acc += sm.v[a0+2]*ftanh(e4.z + sm.u.a.sc[a0+2]);
        acc += sm.v[a0+3]*ftanh(e4.w + sm.u.a.sc[a0+3]);
      }
      acc += __shfl_down(acc, 4, 8);
      acc += __shfl_down(acc, 2, 8);
      acc += __shfl_down(acc, 1, 8);
      if (as == 0) sm.u.a.lw[tl] = __expf(acc) * kScale;
    }
    __syncthreads();
    {
      float c0=0.f, c1=0.f;
      #pragma unroll
      for (int j=0;j<32;++j){
        float w = sm.u.a.lw[j];
        c0 += w*ev[j].x; c1 += w*ev[j].y;
      }
      u64* cp = ctxp + (((size_t)r*kB + bA)*16 + tc)*512 + 2*tid;
      st_nt(cp,   pk(c0, t+1));
      st_nt(cp+1, pk(c1, t+1));
      if (tid == 0){
        float ds = 0.f;
        #pragma unroll
        for (int j=0;j<32;++j) ds += sm.u.a.lw[j];
        st_nt(&dsp[((size_t)r*kB + bA)*16 + tc], pk(ds, t+1));
      }
    }
    __syncthreads();   // union SA -> SC transition (lw reads done before xt writes)
    // ---- R: one block per batch sums the 16 partials ----
    if (isR){
      const u64* pb  = ctxp + ((size_t)r*kB + bA)*16*512 + 2*tid;
      const u64* dpp = dsp + ((size_t)r*kB + bA)*16 + (tid & 15);
      u64 pvx[16], pvy[16], dv;
      int guard = 0;
      for (;;){
        bool ok = true;
        #pragma unroll
        for (int j=0;j<16;++j){
          pvx[j] = ld_nt(pb + (size_t)j*512);
          pvy[j] = ld_nt(pb + (size_t)j*512 + 1);
          ok &= (ptag(pvx[j]) >= t+1) & (ptag(pvy[j]) >= t+1);
        }
        dv = ld_nt(dpp); ok &= (ptag(dv) >= t+1);
        if (__all((int)ok)) break;
        if (ld_ni(abortf) != 0) break;
        if (++guard > (1<<20)){ st_ni(abortf,1); break; }
      }
      float s0=0.f, s1=0.f;
      #pragma unroll
      for (int j=0;j<16;++j){ s0 += payf(pvx[j]); s1 += payf(pvy[j]); }
      u64* cbp = ctxb + ((size_t)r*kB + bA)*512 + 2*tid;
      st_nt(cbp,   pk(s0, t+1));
      st_nt(cbp+1, pk(s1, t+1));
      float d = payf(dv);
      d += __shfl_down(d, 8, 16);
      d += __shfl_down(d, 4, 16);
      d += __shfl_down(d, 2, 16);
      d += __shfl_down(d, 1, 16);
      if (tid == 0) st_nt(&den[(size_t)r*kB + bA], pk(d, t+1));
    }
    // ---- C: poll-gather reduced ctx + den (tags >= t+1), LSTM cell (fp32) ----
    {
      float cux[16], cuy[16], rv;
      {
        const u64* cb = ctxb + ((size_t)r*kB + half*16)*512 + 2*tid;
        const u64* dp = den + (size_t)r*kB + half*16 + b_lC;
        u64 vx[16], vy[16], dv;
        int guard = 0;
        for (;;){
          bool ok = true;
          dv = ld_nt(dp); ok &= (ptag(dv) >= t+1);
          #pragma unroll
          for (int b=0;b<16;++b){
            vx[b] = ld_nt(cb + (size_t)b*512);
            vy[b] = ld_nt(cb + (size_t)b*512 + 1);
            ok &= (ptag(vx[b]) >= t+1) & (ptag(vy[b]) >= t+1);
          }
          if (__all((int)ok)) break;
          if (ld_ni(abortf) != 0) break;
          if (++guard > (1<<20)){ st_ni(abortf,1); break; }
        }
        #pragma unroll
        for (int b=0;b<16;++b){ cux[b] = payf(vx[b]); cuy[b] = payf(vy[b]); }
        rv = frcp(payf(dv));
      }
      float accc=0.f, acch=0.f;
      #pragma unroll
      for (int kc=0; kc<4; ++kc){
        if ((kc & 1) == mych){
          if (kc < 2){
            #pragma unroll
            for (int b=0;b<16;++b){ sm.u.c.xt[b][off] = cux[b]; sm.u.c.xt[b][off+1] = cuy[b]; }
          } else {
            #pragma unroll
            for (int b=0;b<16;++b){ sm.u.c.xt[b][off] = hux[b]; sm.u.c.xt[b][off+1] = huy[b]; }
          }
        }
        __syncthreads();
        {
          const float4* wc4 = (const float4*)(&sm.wsl[wrow][kc*256 + ksC*128]);
          const float4* xv  = (const float4*)(&sm.u.c.xt[b_lC][ksC*128]);
          float a0=0.f, a1=0.f, a2=0.f, a3=0.f;
          #pragma unroll 8
          for (int q=0;q<32;++q){
            float4 w = wc4[q], v = xv[q];
            a0 += w.x*v.x; a1 += w.y*v.y; a2 += w.z*v.z; a3 += w.w*v.w;
          }
          float a = (a0+a1)+(a2+a3);
          if (kc < 2) accc += a; else acch += a;
        }
        __syncthreads();
      }
      sm.u.c.zb[col_l][ksC] = accc*rv + acch;
      __syncthreads();
      if (tid < 32){
        int base = (tid>>1)*8 + (tid&1);
        int e = e0c + (tid&1), b2 = half*16 + (tid>>1);
        float zi = sm.u.c.zb[base+0][0] + sm.u.c.zb[base+0][1] + dbi;
        float zf = sm.u.c.zb[base+2][0] + sm.u.c.zb[base+2][1] + dbf;
        float zg = sm.u.c.zb[base+4][0] + sm.u.c.zb[base+4][1] + dbg;
        float zo = sm.u.c.zb[base+6][0] + sm.u.c.zb[base+6][1] + dbo;
        float c2 = fsig(zf)*cregD + fsig(zi)*ftanh(zg);
        cregD = c2;
        float h = fsig(zo)*ftanh(c2);
        st_nt(&hseq[((size_t)rn*kB + b2)*kHD + e], pk(h, t+1));   // tagged publish, no stamp
        out[((size_t)b2*kT + t)*kHD + e] = h;
      }
    }
    r = rn;
  }
}

extern "C" void kernel_launch(void* const* d_in, const int* in_sizes, int n_in,
                              void* d_out, int out_size, void* d_ws, size_t ws_size,
                              hipStream_t stream) {
  (void)in_sizes; (void)n_in; (void)out_size; (void)ws_size; // needs ws >= ~56 MB
  const float* x     = (const float*)d_in[0];
  const float* eWih  = (const float*)d_in[1];
  const float* eWhh  = (const float*)d_in[2];
  const float* eBih  = (const float*)d_in[3];
  const float* eBhh  = (const float*)d_in[4];
  const float* WencW = (const float*)d_in[5];
  const float* WencB = (const float*)d_in[6];
  const float* WdecW = (const float*)d_in[7];
  const float* WdecB = (const float*)d_in[8];
  const float* Vw    = (const float*)d_in[9];
  const float* attnB = (const float*)d_in[11];
  const float* dWih  = (const float*)d_in[12];
  const float* dWhh  = (const float*)d_in[13];
  const float* dBih  = (const float*)d_in[14];
  const float* dBhh  = (const float*)d_in[15];
  float* ws = (float*)d_ws;
  int* ctr = (int*)(ws + oCtr);
  hipMemsetAsync(ctr, 0, 8192, stream);
  hipLaunchKernelGGL(init_kernel, dim3(512), dim3(256), 0, stream,
                     eBih, eBhh, WdecW, WdecB, attnB, dWih, dWhh, dBih, dBhh, ws);
  hipLaunchKernelGGL(enc_kernel, dim3(256), dim3(256), 0, stream, x, eWih, eWhh, ws);
  hipLaunchKernelGGL(encproj_kernel, dim3(512), dim3(256), 0, stream, WencW, WencB, ws);
  hipLaunchKernelGGL(dec_kernel, dim3(512), dim3(256), 0, stream, Vw, dWih, (float*)d_out, ws);
}

// Round 5
// 18908.841 us; speedup vs baseline: 1.3578x; 1.3578x over previous
//
#include <hip/hip_runtime.h>
#include <stdint.h>

#define DEV __device__ __forceinline__

namespace {

constexpr int kT = 512, kB = 32, kF = 128, kHE = 512, kHD = 512, kA = 256;

typedef _Float16 f16;
typedef _Float16 h4 __attribute__((ext_vector_type(4)));
typedef unsigned long long u64;

// ---- workspace layout (float-unit offsets) ----
constexpr size_t oWdecC  = 0;                          // f32 [2048][512] = Wih[:,512:]+Whh
constexpr size_t oWdWH   = oWdecC + 1048576;           // f16 [256][512]  = WdecW
constexpr size_t oEncSt  = oWdWH + 65536;              // f32 [32][512][512]
constexpr size_t oEncPr  = oEncSt + 8388608;           // f32 [32*512][256]
constexpr size_t oHseq   = oEncPr + 4194304;           // u64 [3][32][512] tagged decoder h
constexpr size_t oEbias  = oHseq + 98304;              // 2048
constexpr size_t oDbias  = oEbias + 2048;              // 2048
constexpr size_t oAb2    = oDbias + 2048;              // 256
constexpr size_t oCtr    = oAb2 + 256;                 // 2048 ints: [0]=abort,[16]=gate1,
                                                       // [576..1087]=slotA, [1088..1599]=slotB,
                                                       // [1856..1887]=slotR
constexpr size_t oHenc   = oCtr + 2048;                // u64 [2][32][512] tagged encoder h
// aliased into encst (dead after dec gate1; all reads flag-guarded, no tags needed):
constexpr size_t aCtxP   = oEncSt;                     // f32 [3][32][16][512] ctx partials
constexpr size_t aScp    = aCtxP + 786432;             // f32 [32][16][256]    dscore partials
constexpr size_t aCtxB   = aScp + 131072;              // f32 [3][32][512]     reduced ctx
constexpr size_t aDsp    = aCtxB + 49152;              // f32 [3][32][16]      denom partials
constexpr size_t aDen    = aDsp + 1536;                // f32 [3][32]          reduced denom

constexpr float kScale = 1.0f/64.0f;

DEV float frcp(float x){ return __builtin_amdgcn_rcpf(x); }
DEV float fsig(float x){ return frcp(1.f + __expf(-x)); }
DEV float ftanh(float x){ return 1.f - 2.f*frcp(__expf(2.f*x) + 1.f); }

// relaxed agent-scope (MALL-coherent) accessors
DEV float ld_na(const float* p){ return __hip_atomic_load((float*)p, __ATOMIC_RELAXED, __HIP_MEMORY_SCOPE_AGENT); }
DEV void  st_na(float* p, float v){ __hip_atomic_store(p, v, __ATOMIC_RELAXED, __HIP_MEMORY_SCOPE_AGENT); }
DEV int   ld_ni(const int* p){ return __hip_atomic_load((int*)p, __ATOMIC_RELAXED, __HIP_MEMORY_SCOPE_AGENT); }
DEV void  st_ni(int* p, int v){ __hip_atomic_store(p, v, __ATOMIC_RELAXED, __HIP_MEMORY_SCOPE_AGENT); }
DEV u64   ld_nt(const u64* p){ return __hip_atomic_load((u64*)p, __ATOMIC_RELAXED, __HIP_MEMORY_SCOPE_AGENT); }
DEV void  st_nt(u64* p, u64 v){ __hip_atomic_store(p, v, __ATOMIC_RELAXED, __HIP_MEMORY_SCOPE_AGENT); }
DEV float2 ld_na2(const float* p){
  u64 v = __hip_atomic_load((const u64*)p, __ATOMIC_RELAXED, __HIP_MEMORY_SCOPE_AGENT);
  union { u64 u; float2 f; } cv; cv.u = v; return cv.f;
}
DEV void st_na2(float* p, float2 v){
  union { float2 f; u64 u; } cv; cv.f = v;
  __hip_atomic_store((u64*)p, cv.u, __ATOMIC_RELAXED, __HIP_MEMORY_SCOPE_AGENT);
}

DEV u64 pk(float v, int tag){ union{float f; uint32_t u;} c; c.f = v; return ((u64)(uint32_t)tag << 32) | (u64)c.u; }
DEV float payf(u64 x){ union{uint32_t u; float f;} c; c.u = (uint32_t)x; return c.f; }
DEV int   ptag(u64 x){ return (int)(x >> 32); }

// distributed slot barrier: wave0 sweeps cnt slots with coalesced relaxed loads
DEV void wait_slots(const int* base, int cnt, int tgt, int* abortf){
  if (threadIdx.x < 64){
    int lane = threadIdx.x;
    int guard = 0;
    for (;;){
      int ok = 1;
      for (int i = lane; i < cnt; i += 64) ok &= (ld_ni(base + i) >= tgt);
      if (__all(ok)) break;
      if (ld_ni(abortf) != 0) break;
      if (++guard > (1<<21)){ st_ni(abortf, 1); break; }
      __builtin_amdgcn_s_sleep(1);
    }
  }
  __syncthreads();
}
// single-counter poll (one-time gate only)
DEV void wait_count(const int* p, int tgt, int* abortf){
  if (threadIdx.x < 64){
    int guard = 0;
    for (;;){
      if (ld_ni(p) >= tgt) break;
      if (ld_ni(abortf) != 0) break;
      if (++guard > (1<<21)){ st_ni(abortf, 1); break; }
      __builtin_amdgcn_s_sleep(2);
    }
  }
  __syncthreads();
}
// arrive: __syncthreads drains each wave's outstanding stores before the stamp issues
DEV void stamp_slot(int* slot, int v){
  __syncthreads();
  if (threadIdx.x == 0) st_ni(slot, v);
}

} // namespace

// ================= kernel 1: init / weight packing =================
__global__ __launch_bounds__(256) void init_kernel(
    const float* __restrict__ eBih, const float* __restrict__ eBhh,
    const float* __restrict__ WdecW, const float* __restrict__ WdecB, const float* __restrict__ attnB,
    const float* __restrict__ dWih, const float* __restrict__ dWhh,
    const float* __restrict__ dBih, const float* __restrict__ dBhh,
    float* __restrict__ ws)
{
  float* whc = ws + oWdecC;            // fp32 [2048][512] = Wih[:,512:] + Whh
  f16* wdwh  = (f16*)(ws + oWdWH);
  u64* hseq  = (u64*)(ws + oHseq);
  u64* henc  = (u64*)(ws + oHenc);
  float* ebias = ws + oEbias;
  float* dbias = ws + oDbias;
  float* ab2w  = ws + oAb2;
  const int gid = blockIdx.x*256 + threadIdx.x;
  const int stride = gridDim.x*256;
  for (int i=gid; i<2048*512; i+=stride){
    int col = i>>9, k = i&511;
    whc[i] = dWih[((size_t)col<<10) + 512 + k] + dWhh[((size_t)col<<9) + k];
  }
  for (int i=gid; i<256*512; i+=stride)  wdwh[i] = (f16)WdecW[i];
  for (int i=gid; i<2048; i+=stride){ ebias[i] = eBih[i]+eBhh[i]; dbias[i] = dBih[i]+dBhh[i]; }
  for (int i=gid; i<256; i+=stride)  ab2w[i] = WdecB[i]+attnB[i];
  // encoder h: both buffers zero (value 0, tag 0)
  for (int i=gid; i<2*kB*kHE; i+=stride) henc[i] = 0ull;
  // decoder h: buffer 0 = initial h tagged 0; buffers 1,2 tag 0
  for (int i=gid; i<kB*kHD; i+=stride){
    int e = i & 511;
    float zi = dBih[e]+dBhh[e];
    float zg = dBih[1024+e]+dBhh[1024+e];
    float zo = dBih[1536+e]+dBhh[1536+e];
    float c0 = fsig(zi)*ftanh(zg);
    hseq[i] = pk(fsig(zo)*ftanh(c0), 0);
  }
  for (int i=gid; i<2*kB*kHD; i+=stride) hseq[kB*kHD + i] = 0ull;
}

// ================= kernel 2: encoder — tagged h exchange (measured ≈ flags) =================
__global__ __launch_bounds__(256, 1) void enc_kernel(
    const float* __restrict__ x, const float* __restrict__ eWih,
    const float* __restrict__ eWhh, float* __restrict__ ws)
{
  constexpr int WP = 644;
  constexpr int XP = 648;
  __shared__ float wsm[32*WP];
  __shared__ float xh[8*XP];
  __shared__ float zs[8][32];
  const float* ebias = ws + oEbias;
  float* encst = ws + oEncSt;
  u64* hq = (u64*)(ws + oHenc);
  int* ctr = (int*)(ws + oCtr);
  int* abortf = ctr;

  const int tid = threadIdx.x, bid = blockIdx.x;
  const int q = bid >> 6, j = bid & 63;    // b-group, e-slice
  const int b0 = q*8, e0 = j*8;

  for (int i = tid; i < 32*640; i += 256){
    int r = i / 640, k = i - r*640;
    int gate = r >> 3, el = r & 7;
    int grow = gate*kHE + e0 + el;
    float v = (k < kF) ? eWih[(size_t)grow*kF + k] : eWhh[(size_t)grow*kHE + (k - kF)];
    wsm[r*WP + k] = v;
  }
  const int b_l = tid >> 5, row = tid & 31;
  const float biasr = ebias[(row>>3)*kHE + e0 + (row&7)];
  const int b_p = tid >> 3, e_p = tid & 7;
  float creg = 0.f;
  __syncthreads();

  int p = 0;
  for (int t = 0; t < kT; ++t){
    __syncthreads();   // protect xh/zs reuse across iterations
    {
      int bl2 = tid >> 5, q4 = tid & 31;
      *(float4*)(&xh[bl2*XP + 4*q4]) = ((const float4*)(x + ((size_t)(b0+bl2)*kT + t)*kF))[q4];
    }
    // tagged h gather: 16 values/thread, poll until tags >= t
    {
      u64 gv[16];
      int guard = 0;
      for (;;){
        bool ok = true;
        #pragma unroll
        for (int i2=0;i2<16;++i2){
          int idx = tid + 256*i2; int bl2 = idx>>9, col = idx&511;
          gv[i2] = ld_nt(&hq[(size_t)p*kB*kHE + (size_t)(b0+bl2)*kHE + col]);
          ok &= (ptag(gv[i2]) >= t);
        }
        if (__all((int)ok)) break;
        if (ld_ni(abortf) != 0) break;
        if (++guard > (1<<20)){ st_ni(abortf, 1); break; }
      }
      #pragma unroll
      for (int i2=0;i2<16;++i2){
        int idx = tid + 256*i2; int bl2 = idx>>9, col = idx&511;
        xh[bl2*XP + kF + col] = payf(gv[i2]);
      }
    }
    __syncthreads();
    {
      const float4* wr = (const float4*)(&wsm[row*WP]);
      const float4* xr = (const float4*)(&xh[b_l*XP]);
      float a0=0.f, a1=0.f, a2=0.f, a3=0.f;
      #pragma unroll 8
      for (int kq = 0; kq < 160; ++kq){
        float4 w = wr[kq], v = xr[kq];
        a0 += w.x*v.x; a1 += w.y*v.y; a2 += w.z*v.z; a3 += w.w*v.w;
      }
      zs[b_l][row] = (a0+a1)+(a2+a3) + biasr;
    }
    __syncthreads();
    if (tid < 64){
      float zi = zs[b_p][0*8 + e_p];
      float zf = zs[b_p][1*8 + e_p];
      float zg = zs[b_p][2*8 + e_p];
      float zo = zs[b_p][3*8 + e_p];
      float c2 = fsig(zf)*creg + fsig(zi)*ftanh(zg);
      creg = c2;
      float h = fsig(zo)*ftanh(c2);
      int b = b0 + b_p, e = e0 + e_p;
      st_nt(&hq[(size_t)(p^1)*kB*kHE + (size_t)b*kHE + e], pk(h, t+1));
      encst[((size_t)b*kT + t)*kHE + e] = h;   // plain; published at kernel end
    }
    p ^= 1;
  }
}

// ================= kernel 3: enc_proj = enc_states @ Wenc^T + b =================
__global__ __launch_bounds__(256) void encproj_kernel(
    const float* __restrict__ WencW, const float* __restrict__ WencB,
    float* __restrict__ ws)
{
  const float* encst = ws + oEncSt;
  float* encpr = ws + oEncPr;
  __shared__ float4 et[32][32];
  const int tid = threadIdx.x, bid = blockIdx.x;
  const int r0 = bid*32;
  float acc[32];
  #pragma unroll
  for (int i=0;i<32;++i) acc[i]=0.f;
  for (int kt=0; kt<4; ++kt){
    #pragma unroll
    for (int i2=0;i2<4;++i2){
      int q = tid + i2*256;
      int row = q>>5, qi = q&31;
      et[row][qi] = ((const float4*)(encst + ((size_t)(r0+row))*kHE + kt*128))[qi];
    }
    __syncthreads();
    const float4* wv = (const float4*)(WencW + (size_t)tid*kHE + kt*128);
    #pragma unroll 1
    for (int q=0;q<32;++q){
      float4 w = wv[q];
      #pragma unroll
      for (int i=0;i<32;++i){
        float4 e4 = et[i][q];
        acc[i] += e4.x*w.x + e4.y*w.y + e4.z*w.z + e4.w*w.w;
      }
    }
    __syncthreads();
  }
  float bb = WencB[tid];
  #pragma unroll
  for (int i=0;i<32;++i) encpr[((size_t)(r0+i))*kA + tid] = acc[i] + bb;
}

// ================= kernel 4: decoder — flags for bulk hops, tagged h only =================
// Chain per step: h --tagged--> A (dscore partial) --slotA--> B (lw, ctx partial)
// --slotB--> R (reduce, 1 block/batch) --slotR--> C (LSTM, publishes tagged h).
namespace {
struct SA  { float h[32]; float sc[256]; float lw[32]; };
struct SC  { float xt[16][260]; float zb[128][2]; };
struct __align__(16) SmemDec {
  float wsl[8][1028];      // fp32 weight slab: rows (gate*2+e_l), K=1024 (ctx|h)
  float v[256];
  union { SA a; SC c; } u;
};
}

__global__ __launch_bounds__(256, 2) void dec_kernel(
    const float* __restrict__ Vw, const float* __restrict__ dWih,
    float* __restrict__ out, float* __restrict__ ws)
{
  __shared__ SmemDec sm;
  const int tid = threadIdx.x, bid = blockIdx.x;
  const float* whc = ws + oWdecC;
  const f16* wdwh  = (const f16*)(ws + oWdWH);
  const float* encst = ws + oEncSt;
  const float* encpr = ws + oEncPr;
  u64* hseq = (u64*)(ws + oHseq);
  float* ctxp = ws + aCtxP;
  float* scp  = ws + aScp;
  float* ctxb = ws + aCtxB;
  float* dsp  = ws + aDsp;
  float* den  = ws + aDen;
  const float* dbias = ws + oDbias;
  const float* ab2w  = ws + oAb2;
  int* ctr   = (int*)(ws + oCtr);
  int* abortf = ctr;
  int* gate1 = ctr + 16;
  int* slotA = ctr + 576;    // [32][16] by (b, tc)
  int* slotB = ctr + 1088;   // [32][16] by (b, tc)
  int* slotR = ctr + 1856;   // [32] by b

  const int bA = bid >> 4, tc = bid & 15, t0a = tc*32;      // A/B role
  const int half = bid >> 8, ecp = bid & 255, e0c = ecp*2;  // C role
  const bool isR = (tc == 0);
  const int col_l = tid & 127, ksC = tid >> 7;
  const int e_lC = col_l & 1, gateC = (col_l>>1)&3, b_lC = col_l>>3;
  const int wrow = gateC*2 + e_lC;

  // ---- one-time: weight slab (8 cols x 1024 K) -> LDS
  for (int i = tid; i < 8*1024; i += 256){
    int rr = i >> 10, k = i & 1023;
    int col = (rr>>1)*kHD + e0c + (rr&1);
    float v = (k < 512) ? dWih[(size_t)col*1024 + k] : whc[(size_t)col*512 + (k-512)];
    sm.wsl[rr][k] = v;
  }
  sm.v[tid] = Vw[tid];

  // ---- one-time register residents (step-invariant)
  h4 wA[8];
  { const h4* wv0 = (const h4*)(wdwh + (size_t)tid*kHD + t0a);
    #pragma unroll
    for (int q=0;q<8;++q) wA[q] = wv0[q]; }
  const int tl = tid>>3, as = tid&7;
  float4 eprR[8];
  { const float* eb2 = encpr + ((size_t)bA*kT + t0a + tl)*kA + as*4;
    #pragma unroll
    for (int q=0;q<8;++q) eprR[q] = *(const float4*)(eb2 + q*32); }
  float2 ev[32];                                   // encoder-state tile in regs
  { const float* eb = encst + ((size_t)bA*kT + t0a)*kHE + 2*tid;
    #pragma unroll
    for (int j=0;j<32;++j) ev[j] = *(const float2*)(eb + (size_t)j*kHE); }

  const float ab2r = ab2w[tid];
  float cregD=0, dbi=0, dbf=0, dbg=0, dbo=0;
  if (tid < 32){
    int e = e0c + (tid&1);
    dbi = dbias[e]; dbf = dbias[512+e]; dbg = dbias[1024+e]; dbo = dbias[1536+e];
    cregD = fsig(dbi)*ftanh(dbg);
  }
  // ---- gate1: all blocks' encst/encpr register loads complete before alias writes
  __syncthreads();
  if (tid == 0) atomicAdd(gate1, 1);
  wait_count(gate1, 512, abortf);

  const int off  = (2*tid) & 255;
  const int mych = tid >> 7;

  int r = 0;
  for (int t=0; t<kT; ++t){
    const int rn = (r==2) ? 0 : r+1;
    __syncthreads();   // union SC (prev step) -> SA transition
    // ---- A: tagged poll of h window (32 contiguous u64 = 4 lines) ----
    if (tid < 32){
      const u64* hp = hseq + ((size_t)r*kB + bA)*kHE + t0a + tid;
      u64 v; int guard = 0;
      for (;;){ v = ld_nt(hp); if (ptag(v) >= t) break;
                if (ld_ni(abortf) != 0) break;
                if (++guard > (1<<20)){ st_ni(abortf,1); break; } }
      sm.u.a.h[tid] = payf(v);
    }
    __syncthreads();
    {
      float sp = 0.f;
      #pragma unroll
      for (int q=0;q<8;++q){
        h4 w = wA[q];
        sp += (float)w.x*sm.u.a.h[q*4+0] + (float)w.y*sm.u.a.h[q*4+1]
            + (float)w.z*sm.u.a.h[q*4+2] + (float)w.w*sm.u.a.h[q*4+3];
      }
      st_na(&scp[((size_t)bA*16 + tc)*kA + tid], sp);
    }
    stamp_slot(&slotA[bA*16 + tc], t+1);
    // ---- B: wait 16 dscore partials (1 flag line), gather, logits, lw, ctx partial ----
    wait_slots(slotA + bA*16, 16, t+1, abortf);
    {
      float sc = ab2r;
      #pragma unroll
      for (int j=0;j<16;++j) sc += ld_na(&scp[((size_t)bA*16 + j)*kA + tid]);
      sm.u.a.sc[tid] = sc;
    }
    __syncthreads();
    {
      float acc = 0.f;
      #pragma unroll
      for (int q=0;q<8;++q){
        int a0 = q*32 + as*4;
        float4 e4 = eprR[q];
        acc += sm.v[a0+0]*ftanh(e4.x + sm.u.a.sc[a0+0]);
        acc += sm.v[a0+1]*ftanh(e4.y + sm.u.a.sc[a0+1]);
        acc += sm.v[a0+2]*ftanh(e4.z + sm.u.a.sc[a0+2]);
        acc += sm.v[a0+3]*ftanh(e4.w + sm.u.a.sc[a0+3]);
      }
      acc += __shfl_down(acc, 4, 8);
      acc += __shfl_down(acc, 2, 8);
      acc += __shfl_down(acc, 1, 8);
      if (as == 0) sm.u.a.lw[tl] = __expf(acc) * kScale;
    }
    __syncthreads();
    {
      float c0=0.f, c1=0.f;
      #pragma unroll
      for (int j=0;j<32;++j){
        float w = sm.u.a.lw[j];
        c0 += w*ev[j].x; c1 += w*ev[j].y;
      }
      st_na2(&ctxp[(((size_t)r*kB + bA)*16 + tc)*kHE + 2*tid], make_float2(c0, c1));
      if (tid == 0){
        float ds = 0.f;
        #pragma unroll
        for (int j=0;j<32;++j) ds += sm.u.a.lw[j];
        st_na(&dsp[((size_t)r*kB + bA)*16 + tc], ds);
      }
    }
    stamp_slot(&slotB[bA*16 + tc], t+1);
    // ---- R: one block per batch sums the 16 partials ----
    if (isR){
      wait_slots(slotB + bA*16, 16, t+1, abortf);
      {
        const float* pb = ctxp + ((size_t)r*kB + bA)*16*kHE + 2*tid;
        float s0=0.f, s1=0.f;
        #pragma unroll
        for (int j=0;j<16;++j){
          float2 p = ld_na2(pb + (size_t)j*kHE);
          s0 += p.x; s1 += p.y;
        }
        st_na2(&ctxb[((size_t)r*kB + bA)*kHE + 2*tid], make_float2(s0, s1));
        float d = (tid < 16) ? ld_na(&dsp[((size_t)r*kB + bA)*16 + tid]) : 0.f;
        d += __shfl_down(d, 8, 16);
        d += __shfl_down(d, 4, 16);
        d += __shfl_down(d, 2, 16);
        d += __shfl_down(d, 1, 16);
        if (tid == 0) st_na(&den[r*kB + bA], d);
      }
      stamp_slot(&slotR[bA], t+1);
    }
    // ---- C: wait the half's 16 reducers (1 flag line), gather, LSTM (fp32) ----
    wait_slots(slotR + half*16, 16, t+1, abortf);
    {
      const float rv = frcp(ld_na(&den[r*kB + half*16 + b_lC]));
      // one-shot overlapped gathers: reduced ctx + tagged h rows (ordered by slotR chain)
      const float* cbase = ctxb + (size_t)r*kB*kHE + (size_t)(half*16)*kHE + 2*tid;
      const u64*   hbase = hseq + ((size_t)r*kB + half*16)*kHE + 2*tid;
      float cux[16], cuy[16], hux[16], huy[16];
      #pragma unroll
      for (int b=0;b<16;++b){
        float2 cv = ld_na2(cbase + (size_t)b*kHE);
        cux[b] = cv.x; cuy[b] = cv.y;
        hux[b] = payf(ld_nt(hbase + (size_t)b*kHE));
        huy[b] = payf(ld_nt(hbase + (size_t)b*kHE + 1));
      }
      float accc=0.f, acch=0.f;
      #pragma unroll
      for (int kc=0; kc<4; ++kc){
        if ((kc & 1) == mych){
          if (kc < 2){
            #pragma unroll
            for (int b=0;b<16;++b){ sm.u.c.xt[b][off] = cux[b]; sm.u.c.xt[b][off+1] = cuy[b]; }
          } else {
            #pragma unroll
            for (int b=0;b<16;++b){ sm.u.c.xt[b][off] = hux[b]; sm.u.c.xt[b][off+1] = huy[b]; }
          }
        }
        __syncthreads();
        {
          const float4* wc4 = (const float4*)(&sm.wsl[wrow][kc*256 + ksC*128]);
          const float4* xv  = (const float4*)(&sm.u.c.xt[b_lC][ksC*128]);
          float a0=0.f, a1=0.f, a2=0.f, a3=0.f;
          #pragma unroll 8
          for (int q=0;q<32;++q){
            float4 w = wc4[q], v = xv[q];
            a0 += w.x*v.x; a1 += w.y*v.y; a2 += w.z*v.z; a3 += w.w*v.w;
          }
          float a = (a0+a1)+(a2+a3);
          if (kc < 2) accc += a; else acch += a;
        }
        __syncthreads();
      }
      sm.u.c.zb[col_l][ksC] = accc*rv + acch;
      __syncthreads();
      if (tid < 32){
        int base = (tid>>1)*8 + (tid&1);
        int e = e0c + (tid&1), b2 = half*16 + (tid>>1);
        float zi = sm.u.c.zb[base+0][0] + sm.u.c.zb[base+0][1] + dbi;
        float zf = sm.u.c.zb[base+2][0] + sm.u.c.zb[base+2][1] + dbf;
        float zg = sm.u.c.zb[base+4][0] + sm.u.c.zb[base+4][1] + dbg;
        float zo = sm.u.c.zb[base+6][0] + sm.u.c.zb[base+6][1] + dbo;
        float c2 = fsig(zf)*cregD + fsig(zi)*ftanh(zg);
        cregD = c2;
        float h = fsig(zo)*ftanh(c2);
        st_nt(&hseq[((size_t)rn*kB + b2)*kHD + e], pk(h, t+1));   // tagged publish
        out[((size_t)b2*kT + t)*kHD + e] = h;
      }
    }
    r = rn;
  }
}

extern "C" void kernel_launch(void* const* d_in, const int* in_sizes, int n_in,
                              void* d_out, int out_size, void* d_ws, size_t ws_size,
                              hipStream_t stream) {
  (void)in_sizes; (void)n_in; (void)out_size; (void)ws_size; // needs ws >= ~56 MB
  const float* x     = (const float*)d_in[0];
  const float* eWih  = (const float*)d_in[1];
  const float* eWhh  = (const float*)d_in[2];
  const float* eBih  = (const float*)d_in[3];
  const float* eBhh  = (const float*)d_in[4];
  const float* WencW = (const float*)d_in[5];
  const float* WencB = (const float*)d_in[6];
  const float* WdecW = (const float*)d_in[7];
  const float* WdecB = (const float*)d_in[8];
  const float* Vw    = (const float*)d_in[9];
  const float* attnB = (const float*)d_in[11];
  const float* dWih  = (const float*)d_in[12];
  const float* dWhh  = (const float*)d_in[13];
  const float* dBih  = (const float*)d_in[14];
  const float* dBhh  = (const float*)d_in[15];
  float* ws = (float*)d_ws;
  int* ctr = (int*)(ws + oCtr);
  hipMemsetAsync(ctr, 0, 8192, stream);
  hipLaunchKernelGGL(init_kernel, dim3(512), dim3(256), 0, stream,
                     eBih, eBhh, WdecW, WdecB, attnB, dWih, dWhh, dBih, dBhh, ws);
  hipLaunchKernelGGL(enc_kernel, dim3(256), dim3(256), 0, stream, x, eWih, eWhh, ws);
  hipLaunchKernelGGL(encproj_kernel, dim3(512), dim3(256), 0, stream, WencW, WencB, ws);
  hipLaunchKernelGGL(dec_kernel, dim3(512), dim3(256), 0, stream, Vw, dWih, (float*)d_out, ws);
}

// Round 6
// 14982.014 us; speedup vs baseline: 1.7137x; 1.2621x over previous
//
#include <hip/hip_runtime.h>
#include <stdint.h>

#define DEV __device__ __forceinline__

namespace {

constexpr int kT = 512, kB = 32, kF = 128, kHE = 512, kHD = 512, kA = 256;

typedef _Float16 f16;
typedef _Float16 h4 __attribute__((ext_vector_type(4)));
typedef unsigned long long u64;

// ---- workspace layout (float-unit offsets) ----
constexpr size_t oWdecC  = 0;                          // f32 [2048][512] = Wih[:,512:]+Whh
constexpr size_t oWdWH   = oWdecC + 1048576;           // f16 [256][512]  = WdecW
constexpr size_t oEncSt  = oWdWH + 65536;              // f32 [32][512][512]
constexpr size_t oEncPr  = oEncSt + (size_t)kB*kT*kHE; // f32 [32*512][256]
constexpr size_t oHdec   = oEncPr + (size_t)kB*kT*kA;  // f32 [3][32][512]
constexpr size_t oCtx    = oHdec + 3ull*kB*kHD;        // f32 [3][32][512] reduced ctx (x kScale)
constexpr size_t oDen    = oCtx + 3ull*kB*kHE;         // f32 [3][32] reduced denominators
constexpr size_t oScp    = oDen + 96;                  // f32 [32][16][256] dscore partials
constexpr size_t oEbias  = oScp + (size_t)kB*16*kA;    // 2048
constexpr size_t oDbias  = oEbias + 2048;              // 2048
constexpr size_t oAb2    = oDbias + 2048;              // 256
constexpr size_t oCtr    = oAb2 + 256;                 // 2048 ints: [0]=abort, [16]=startgate,
                                                       // [64..575]=slotC, [576..1087]=slotA,
                                                       // [1088..1599]=slotB, [1600..1855]=slotE,
                                                       // [1856..1887]=slotR
constexpr size_t oHenc   = oCtr + 2048;                // f32 [2][32][512] encoder h double buffer
// encst region is DEAD after dec_kernel's start gate (tiles live in registers) -> reuse:
constexpr size_t oCtxP   = oEncSt;                     // f32 [3][32][16][512] ctx partials
constexpr size_t oDenP   = oEncSt + 3ull*32*16*512;    // f32 [3][32][16] denominator partials

constexpr float kScale = 1.0f/64.0f;

DEV float frcp(float x){ return __builtin_amdgcn_rcpf(x); }
DEV float fsig(float x){ return frcp(1.f + __expf(-x)); }
DEV float ftanh(float x){ return 1.f - 2.f*frcp(__expf(2.f*x) + 1.f); }

// relaxed agent-scope (MALL-coherent) accessors
DEV float ld_na(const float* p){ return __hip_atomic_load((float*)p, __ATOMIC_RELAXED, __HIP_MEMORY_SCOPE_AGENT); }
DEV void  st_na(float* p, float v){ __hip_atomic_store(p, v, __ATOMIC_RELAXED, __HIP_MEMORY_SCOPE_AGENT); }
DEV int   ld_ni(const int* p){ return __hip_atomic_load((int*)p, __ATOMIC_RELAXED, __HIP_MEMORY_SCOPE_AGENT); }
DEV void  st_ni(int* p, int v){ __hip_atomic_store(p, v, __ATOMIC_RELAXED, __HIP_MEMORY_SCOPE_AGENT); }
DEV float2 ld_na2(const float* p){
  u64 v = __hip_atomic_load((const u64*)p, __ATOMIC_RELAXED, __HIP_MEMORY_SCOPE_AGENT);
  union { u64 u; float2 f; } cv; cv.u = v; return cv.f;
}
DEV void st_na2(float* p, float2 v){
  union { float2 f; u64 u; } cv; cv.f = v;
  __hip_atomic_store((u64*)p, cv.u, __ATOMIC_RELAXED, __HIP_MEMORY_SCOPE_AGENT);
}

// distributed slot barrier: wave0 sweeps cnt slots with coalesced relaxed loads
DEV void wait_slots(const int* base, int cnt, int tgt, int* abortf){
  if (threadIdx.x < 64){
    int lane = threadIdx.x;
    int guard = 0;
    for (;;){
      int ok = 1;
      for (int i = lane; i < cnt; i += 64) ok &= (ld_ni(base + i) >= tgt);
      if (__all(ok)) break;
      if (ld_ni(abortf) != 0) break;
      if (++guard > (1<<21)){ st_ni(abortf, 1); break; }
      __builtin_amdgcn_s_sleep(1);
    }
  }
  __syncthreads();
}
// single-counter poll (one-time start gate only)
DEV void wait_count(const int* p, int tgt, int* abortf){
  if (threadIdx.x < 64){
    int guard = 0;
    for (;;){
      if (ld_ni(p) >= tgt) break;
      if (ld_ni(abortf) != 0) break;
      if (++guard > (1<<21)){ st_ni(abortf, 1); break; }
      __builtin_amdgcn_s_sleep(2);
    }
  }
  __syncthreads();
}
// arrive: __syncthreads drains each wave's outstanding stores before the stamp issues
DEV void stamp_slot(int* slot, int v){
  __syncthreads();
  if (threadIdx.x == 0) st_ni(slot, v);
}

} // namespace

// ================= kernel 1: init / weight packing =================
__global__ __launch_bounds__(256) void init_kernel(
    const float* __restrict__ eBih, const float* __restrict__ eBhh,
    const float* __restrict__ WdecW, const float* __restrict__ WdecB, const float* __restrict__ attnB,
    const float* __restrict__ dWih, const float* __restrict__ dWhh,
    const float* __restrict__ dBih, const float* __restrict__ dBhh,
    float* __restrict__ ws)
{
  float* whc = ws + oWdecC;            // fp32 [2048][512] = Wih[:,512:] + Whh
  f16* wdwh  = (f16*)(ws + oWdWH);
  float* hdec  = ws + oHdec;
  float* ebias = ws + oEbias;
  float* dbias = ws + oDbias;
  float* ab2w  = ws + oAb2;
  float* henc  = ws + oHenc;
  const int gid = blockIdx.x*256 + threadIdx.x;
  const int stride = gridDim.x*256;
  for (int i=gid; i<2048*512; i+=stride){
    int col = i>>9, k = i&511;
    whc[i] = dWih[((size_t)col<<10) + 512 + k] + dWhh[((size_t)col<<9) + k];
  }
  for (int i=gid; i<256*512; i+=stride)  wdwh[i] = (f16)WdecW[i];
  for (int i=gid; i<2048; i+=stride){ ebias[i] = eBih[i]+eBhh[i]; dbias[i] = dBih[i]+dBhh[i]; }
  for (int i=gid; i<256; i+=stride)  ab2w[i] = WdecB[i]+attnB[i];
  for (int i=gid; i<2*kB*kHE; i+=stride) henc[i] = 0.f;
  for (int i=gid; i<kB*kHD; i+=stride){
    int e = i & 511;
    float zi = dBih[e]+dBhh[e];
    float zg = dBih[1024+e]+dBhh[1024+e];
    float zo = dBih[1536+e]+dBhh[1536+e];
    float c0 = fsig(zi)*ftanh(zg);
    hdec[i] = fsig(zo)*ftanh(c0);   // buffer 0: initial decoder h
  }
}

// ================= kernel 2: encoder — weight-stationary, slot-flag sync =================
__global__ __launch_bounds__(256, 1) void enc_kernel(
    const float* __restrict__ x, const float* __restrict__ eWih,
    const float* __restrict__ eWhh, float* __restrict__ ws)
{
  constexpr int WP = 644;   // w row pad (floats)
  constexpr int XP = 648;   // xh row pad
  __shared__ float wsm[32*WP];
  __shared__ float xh[8*XP];
  __shared__ float zs[8][32];
  const float* ebias = ws + oEbias;
  float* encst = ws + oEncSt;
  float* henc  = ws + oHenc;
  int* ctr = (int*)(ws + oCtr);
  int* abortf = ctr;
  int* slotE = ctr + 1600;

  const int tid = threadIdx.x, bid = blockIdx.x;
  const int q = bid >> 6, j = bid & 63;    // b-group, e-slice
  const int b0 = q*8, e0 = j*8;

  for (int i = tid; i < 32*640; i += 256){
    int r = i / 640, k = i - r*640;
    int gate = r >> 3, el = r & 7;
    int grow = gate*kHE + e0 + el;
    float v = (k < kF) ? eWih[(size_t)grow*kF + k] : eWhh[(size_t)grow*kHE + (k - kF)];
    wsm[r*WP + k] = v;
  }
  const int b_l = tid >> 5, row = tid & 31;       // dot role: (batch, w-row)
  const float biasr = ebias[(row>>3)*kHE + e0 + (row&7)];
  const int b_p = tid >> 3, e_p = tid & 7;        // pointwise role
  float creg = 0.f;
  __syncthreads();

  int p = 0;
  for (int t = 0; t < kT; ++t){
    // stage x_t for 8 batches (independent of h)
    {
      int bl2 = tid >> 5, q4 = tid & 31;
      *(float4*)(&xh[bl2*XP + 4*q4]) = ((const float4*)(x + ((size_t)(b0+bl2)*kT + t)*kF))[q4];
    }
    wait_slots(slotE + q*64, 64, t, abortf);
    // stage h_{t-1} for 8 batches via MALL-coherent loads
    #pragma unroll
    for (int i = 0; i < 4; ++i){
      int idx = tid + 256*i;
      int bl2 = idx >> 7, q4 = idx & 127;
      const float* hsrc = henc + (size_t)p*kB*kHE + (size_t)(b0+bl2)*kHE + 4*q4;
      float4 hv;
      hv.x = ld_na(hsrc); hv.y = ld_na(hsrc+1); hv.z = ld_na(hsrc+2); hv.w = ld_na(hsrc+3);
      *(float4*)(&xh[bl2*XP + kF + 4*q4]) = hv;
    }
    __syncthreads();
    {
      const float4* wr = (const float4*)(&wsm[row*WP]);
      const float4* xr = (const float4*)(&xh[b_l*XP]);
      float a0=0.f, a1=0.f, a2=0.f, a3=0.f;
      #pragma unroll 8
      for (int kq = 0; kq < 160; ++kq){
        float4 w = wr[kq], v = xr[kq];
        a0 += w.x*v.x; a1 += w.y*v.y; a2 += w.z*v.z; a3 += w.w*v.w;
      }
      zs[b_l][row] = (a0+a1)+(a2+a3) + biasr;
    }
    __syncthreads();
    if (tid < 64){
      float zi = zs[b_p][0*8 + e_p];
      float zf = zs[b_p][1*8 + e_p];
      float zg = zs[b_p][2*8 + e_p];
      float zo = zs[b_p][3*8 + e_p];
      float c2 = fsig(zf)*creg + fsig(zi)*ftanh(zg);
      creg = c2;
      float h = fsig(zo)*ftanh(c2);
      int b = b0 + b_p, e = e0 + e_p;
      st_na(&henc[(size_t)(p^1)*kB*kHE + (size_t)b*kHE + e], h);
      encst[((size_t)b*kT + t)*kHE + e] = h;   // plain; published at kernel end
    }
    stamp_slot(&slotE[q*64 + j], t+1);
    p ^= 1;
  }
}

// ================= kernel 3: enc_proj = enc_states @ Wenc^T + b =================
__global__ __launch_bounds__(256) void encproj_kernel(
    const float* __restrict__ WencW, const float* __restrict__ WencB,
    float* __restrict__ ws)
{
  const float* encst = ws + oEncSt;
  float* encpr = ws + oEncPr;
  __shared__ float4 et[32][32];
  const int tid = threadIdx.x, bid = blockIdx.x;
  const int r0 = bid*32;
  float acc[32];
  #pragma unroll
  for (int i=0;i<32;++i) acc[i]=0.f;
  for (int kt=0; kt<4; ++kt){
    #pragma unroll
    for (int i2=0;i2<4;++i2){
      int q = tid + i2*256;
      int row = q>>5, qi = q&31;
      et[row][qi] = ((const float4*)(encst + ((size_t)(r0+row))*kHE + kt*128))[qi];
    }
    __syncthreads();
    const float4* wv = (const float4*)(WencW + (size_t)tid*kHE + kt*128);
    #pragma unroll 1
    for (int q=0;q<32;++q){
      float4 w = wv[q];
      #pragma unroll
      for (int i=0;i<32;++i){
        float4 e4 = et[i][q];
        acc[i] += e4.x*w.x + e4.y*w.y + e4.z*w.z + e4.w*w.w;
      }
    }
    __syncthreads();
  }
  float bb = WencB[tid];
  #pragma unroll
  for (int i=0;i<32;++i) encpr[((size_t)(r0+i))*kA + tid] = acc[i] + bb;
}

// ================= kernel 4: decoder — R3 flag protocol + early h-half GEMV =================
// Chain per step: slotC(16) -> A (dscore partial) -> slotA -> B (lw, ctx partial)
// -> slotB -> R (reduce) -> slotR -> C (ctx-half + pointwise).
// NEW: C-prep (h-half GEMV, kc=2,3) hoisted BEFORE the slotR wait, overlapping R.
namespace {
struct SA  { float h[32]; float sc[256]; float lw[32]; };
struct SC  { float xt[16][260]; float zb[128][2]; };
struct __align__(16) SmemDec {
  float wsl[8][1028];      // fp32 weight slab: rows (gate*2+e_l), K=1024 (ctx|h)
  float v[256];
  SA a;                    // un-unioned: SA live across A/B, SC live across C-prep/C
  SC c;
};
}

__global__ __launch_bounds__(256, 2) void dec_kernel(
    const float* __restrict__ Vw, const float* __restrict__ dWih,
    float* __restrict__ out, float* __restrict__ ws)
{
  __shared__ SmemDec sm;
  const int tid = threadIdx.x, bid = blockIdx.x;
  const float* whc = ws + oWdecC;
  const f16* wdwh  = (const f16*)(ws + oWdWH);
  const float* encst = ws + oEncSt;
  const float* encpr = ws + oEncPr;
  float* hdec = ws + oHdec;
  float* ctxb = ws + oCtx;                        // reduced ctx [3][32][512]
  float* den  = ws + oDen;                        // reduced denom [3][32]
  float* scp  = ws + oScp;
  float* ctxp = ws + oCtxP;                       // partials [3][32][16][512] (aliases encst)
  float* denp = ws + oDenP;                       // partials [3][32][16]
  const float* dbias = ws + oDbias;
  const float* ab2w  = ws + oAb2;
  int* ctr   = (int*)(ws + oCtr);
  int* abortf = ctr;
  int* startc = ctr + 16;
  int* slotC = ctr + 64;     // [2][256] by (half, ecp)
  int* slotA = ctr + 576;    // [32][16] by (b, tc)
  int* slotB = ctr + 1088;   // [32][16] by (b, tc)
  int* slotR = ctr + 1856;   // [32] by b

  const int bA = bid >> 4, tc = bid & 15, t0a = tc*32;      // A/B role
  const int half = bid >> 8, ecp = bid & 255, e0c = ecp*2;  // C role
  const bool isR = (tc == 0);
  const int col_l = tid & 127, ksC = tid >> 7;
  const int e_lC = col_l & 1, gateC = (col_l>>1)&3, b_lC = col_l>>3;
  const int wrow = gateC*2 + e_lC;

  // ---- one-time: weight slab (8 cols x 1024 K) -> LDS
  for (int i = tid; i < 8*1024; i += 256){
    int rr = i >> 10, k = i & 1023;
    int col = (rr>>1)*kHD + e0c + (rr&1);
    float v = (k < 512) ? dWih[(size_t)col*1024 + k] : whc[(size_t)col*512 + (k-512)];
    sm.wsl[rr][k] = v;
  }
  sm.v[tid] = Vw[tid];

  // ---- one-time register residents (step-invariant)
  h4 wA[8];
  { const h4* wv0 = (const h4*)(wdwh + (size_t)tid*kHD + t0a);
    #pragma unroll
    for (int q=0;q<8;++q) wA[q] = wv0[q]; }
  const int tl = tid>>3, as = tid&7;
  float4 eprR[8];
  { const float* eb2 = encpr + ((size_t)bA*kT + t0a + tl)*kA + as*4;
    #pragma unroll
    for (int q=0;q<8;++q) eprR[q] = *(const float4*)(eb2 + q*32); }
  float2 ev[32];                                   // encoder-state tile in regs
  { const float* eb = encst + ((size_t)bA*kT + t0a)*kHE + 2*tid;
    #pragma unroll
    for (int j=0;j<32;++j) ev[j] = *(const float2*)(eb + (size_t)j*kHE); }

  const float ab2r = ab2w[tid];
  float cregD=0, dbi=0, dbf=0, dbg=0, dbo=0;
  if (tid < 32){
    int e = e0c + (tid&1);
    dbi = dbias[e]; dbf = dbias[512+e]; dbg = dbias[1024+e]; dbo = dbias[1536+e];
    cregD = fsig(dbi)*ftanh(dbg);
  }
  // ---- gate: all blocks' encst/encpr register loads complete before alias writes
  __syncthreads();
  if (tid == 0) atomicAdd(startc, 1);
  wait_count(startc, 512, abortf);

  const int off  = (2*tid) & 255;   // col offset within a 256-wide K chunk
  const int mych = tid >> 7;        // which K-half this thread's data belongs to

  int r = 0;
  for (int t=0; t<kT; ++t){
    const int rn = (r==2) ? 0 : r+1;
    // ---- A: wait h producers (16 slots = 1 line), dscore partial ----
    wait_slots(slotC + (bA>>4)*256 + tc*16, 16, t, abortf);
    if (tid < 32) sm.a.h[tid] = ld_na(hdec + (size_t)r*kB*kHD + (size_t)bA*kHD + t0a + tid);
    __syncthreads();
    {
      float sp = 0.f;
      #pragma unroll
      for (int q=0;q<8;++q){
        h4 w = wA[q];
        sp += (float)w.x*sm.a.h[q*4+0] + (float)w.y*sm.a.h[q*4+1]
            + (float)w.z*sm.a.h[q*4+2] + (float)w.w*sm.a.h[q*4+3];
      }
      st_na(&scp[((size_t)bA*16 + tc)*kA + tid], sp);
    }
    stamp_slot(&slotA[bA*16 + tc], t+1);
    // ---- B: wait 16 dscore partials, gather, tanh-logits, exp, ctx partial ----
    wait_slots(slotA + bA*16, 16, t+1, abortf);
    {
      float sc = ab2r;
      #pragma unroll
      for (int j=0;j<16;++j) sc += ld_na(&scp[((size_t)bA*16 + j)*kA + tid]);
      sm.a.sc[tid] = sc;
    }
    __syncthreads();
    {
      float acc = 0.f;
      #pragma unroll
      for (int q=0;q<8;++q){
        int a0 = q*32 + as*4;
        float4 e4 = eprR[q];
        acc += sm.v[a0+0]*ftanh(e4.x + sm.a.sc[a0+0]);
        acc += sm.v[a0+1]*ftanh(e4.y + sm.a.sc[a0+1]);
        acc += sm.v[a0+2]*ftanh(e4.z + sm.a.sc[a0+2]);
        acc += sm.v[a0+3]*ftanh(e4.w + sm.a.sc[a0+3]);
      }
      acc += __shfl_down(acc, 4, 8);
      acc += __shfl_down(acc, 2, 8);
      acc += __shfl_down(acc, 1, 8);
      if (as == 0) sm.a.lw[tl] = __expf(acc) * kScale;
    }
    __syncthreads();
    {
      float c0=0.f, c1=0.f;
      #pragma unroll
      for (int j=0;j<32;++j){
        float w = sm.a.lw[j];
        c0 += w*ev[j].x; c1 += w*ev[j].y;
      }
      st_na2(&ctxp[(((size_t)r*kB + bA)*16 + tc)*kHE + 2*tid], make_float2(c0, c1));
      if (tid == 0){
        float ds = 0.f;
        #pragma unroll
        for (int j=0;j<32;++j) ds += sm.a.lw[j];
        st_na(&denp[((size_t)r*kB + bA)*16 + tc], ds);
      }
    }
    stamp_slot(&slotB[bA*16 + tc], t+1);
    // ---- R: one block per batch sums the 16 partials ----
    if (isR){
      wait_slots(slotB + bA*16, 16, t+1, abortf);
      {
        const float* pb = ctxp + ((size_t)r*kB + bA)*16*kHE + 2*tid;
        float s0=0.f, s1=0.f;
        #pragma unroll
        for (int j=0;j<16;++j){
          float2 p = ld_na2(pb + (size_t)j*kHE);
          s0 += p.x; s1 += p.y;
        }
        st_na2(&ctxb[((size_t)r*kB + bA)*kHE + 2*tid], make_float2(s0, s1));
        float d = (tid < 16) ? ld_na(&denp[((size_t)r*kB + bA)*16 + tid]) : 0.f;
        d += __shfl_down(d, 8, 16);
        d += __shfl_down(d, 4, 16);
        d += __shfl_down(d, 2, 16);
        d += __shfl_down(d, 1, 16);
        if (tid == 0) st_na(&den[r*kB + bA], d);
      }
      stamp_slot(&slotR[bA], t+1);
    }
    // ---- C-prep: h-half of the LSTM GEMV (kc=2,3), overlaps other blocks' R ----
    // h(t) for the whole half is ready once all 256 slotC of the half reach t.
    wait_slots(slotC + half*256, 256, t, abortf);
    float acch = 0.f;
    {
      const float* hbase = hdec + (size_t)r*kB*kHD + (size_t)(half*16)*kHD + 2*tid;
      float hux[16], huy[16];
      #pragma unroll
      for (int b=0;b<16;++b){
        float2 hv = ld_na2(hbase + (size_t)b*kHD);
        hux[b] = hv.x; huy[b] = hv.y;
      }
      #pragma unroll
      for (int kc=2; kc<4; ++kc){
        if ((kc & 1) == mych){
          #pragma unroll
          for (int b=0;b<16;++b){ sm.c.xt[b][off] = hux[b]; sm.c.xt[b][off+1] = huy[b]; }
        }
        __syncthreads();
        {
          const float4* wc4 = (const float4*)(&sm.wsl[wrow][kc*256 + ksC*128]);
          const float4* xv  = (const float4*)(&sm.c.xt[b_lC][ksC*128]);
          float a0=0.f, a1=0.f, a2=0.f, a3=0.f;
          #pragma unroll 8
          for (int q=0;q<32;++q){
            float4 w = wc4[q], v = xv[q];
            a0 += w.x*v.x; a1 += w.y*v.y; a2 += w.z*v.z; a3 += w.w*v.w;
          }
          acch += (a0+a1)+(a2+a3);
        }
        __syncthreads();
      }
    }
    // ---- C: wait the half's 16 reducers (1 flag line), ctx-half + pointwise ----
    wait_slots(slotR + half*16, 16, t+1, abortf);
    {
      const float rv = frcp(ld_na(&den[r*kB + half*16 + b_lC]));
      const float* cbase = ctxb + (size_t)r*kB*kHE + (size_t)(half*16)*kHE + 2*tid;
      float cux[16], cuy[16];
      #pragma unroll
      for (int b=0;b<16;++b){
        float2 cv = ld_na2(cbase + (size_t)b*kHE);
        cux[b] = cv.x; cuy[b] = cv.y;
      }
      float accc = 0.f;
      #pragma unroll
      for (int kc=0; kc<2; ++kc){
        if ((kc & 1) == mych){
          #pragma unroll
          for (int b=0;b<16;++b){ sm.c.xt[b][off] = cux[b]; sm.c.xt[b][off+1] = cuy[b]; }
        }
        __syncthreads();
        {
          const float4* wc4 = (const float4*)(&sm.wsl[wrow][kc*256 + ksC*128]);
          const float4* xv  = (const float4*)(&sm.c.xt[b_lC][ksC*128]);
          float a0=0.f, a1=0.f, a2=0.f, a3=0.f;
          #pragma unroll 8
          for (int q=0;q<32;++q){
            float4 w = wc4[q], v = xv[q];
            a0 += w.x*v.x; a1 += w.y*v.y; a2 += w.z*v.z; a3 += w.w*v.w;
          }
          accc += (a0+a1)+(a2+a3);
        }
        __syncthreads();
      }
      sm.c.zb[col_l][ksC] = accc*rv + acch;
      __syncthreads();
      if (tid < 32){
        int base = (tid>>1)*8 + (tid&1);
        int e = e0c + (tid&1), b2 = half*16 + (tid>>1);
        float zi = sm.c.zb[base+0][0] + sm.c.zb[base+0][1] + dbi;
        float zf = sm.c.zb[base+2][0] + sm.c.zb[base+2][1] + dbf;
        float zg = sm.c.zb[base+4][0] + sm.c.zb[base+4][1] + dbg;
        float zo = sm.c.zb[base+6][0] + sm.c.zb[base+6][1] + dbo;
        float c2 = fsig(zf)*cregD + fsig(zi)*ftanh(zg);
        cregD = c2;
        float h = fsig(zo)*ftanh(c2);
        st_na(&hdec[(size_t)rn*kB*kHD + (size_t)b2*kHD + e], h);
        out[((size_t)b2*kT + t)*kHD + e] = h;
      }
    }
    stamp_slot(&slotC[half*256 + ecp], t+1);
    r = rn;
  }
}

extern "C" void kernel_launch(void* const* d_in, const int* in_sizes, int n_in,
                              void* d_out, int out_size, void* d_ws, size_t ws_size,
                              hipStream_t stream) {
  (void)in_sizes; (void)n_in; (void)out_size; (void)ws_size; // needs ws >= ~56 MB
  const float* x     = (const float*)d_in[0];
  const float* eWih  = (const float*)d_in[1];
  const float* eWhh  = (const float*)d_in[2];
  const float* eBih  = (const float*)d_in[3];
  const float* eBhh  = (const float*)d_in[4];
  const float* WencW = (const float*)d_in[5];
  const float* WencB = (const float*)d_in[6];
  const float* WdecW = (const float*)d_in[7];
  const float* WdecB = (const float*)d_in[8];
  const float* Vw    = (const float*)d_in[9];
  const float* attnB = (const float*)d_in[11];
  const float* dWih  = (const float*)d_in[12];
  const float* dWhh  = (const float*)d_in[13];
  const float* dBih  = (const float*)d_in[14];
  const float* dBhh  = (const float*)d_in[15];
  float* ws = (float*)d_ws;
  int* ctr = (int*)(ws + oCtr);
  hipMemsetAsync(ctr, 0, 8192, stream);
  hipLaunchKernelGGL(init_kernel, dim3(512), dim3(256), 0, stream,
                     eBih, eBhh, WdecW, WdecB, attnB, dWih, dWhh, dBih, dBhh, ws);
  hipLaunchKernelGGL(enc_kernel, dim3(256), dim3(256), 0, stream, x, eWih, eWhh, ws);
  hipLaunchKernelGGL(encproj_kernel, dim3(512), dim3(256), 0, stream, WencW, WencB, ws);
  hipLaunchKernelGGL(dec_kernel, dim3(512), dim3(256), 0, stream, Vw, dWih, (float*)d_out, ws);
}

// Round 8
// 12197.493 us; speedup vs baseline: 2.1049x; 1.2283x over previous
//
#include <hip/hip_runtime.h>
#include <stdint.h>

#define DEV __device__ __forceinline__

namespace {

constexpr int kT = 512, kB = 32, kF = 128, kHE = 512, kHD = 512, kA = 256;

typedef _Float16 f16;
typedef _Float16 h4 __attribute__((ext_vector_type(4)));
typedef unsigned long long u64;

// ---- workspace layout (float-unit offsets) ----
constexpr size_t oWdecC  = 0;                          // f32 [2048][512] = Wih[:,512:]+Whh
constexpr size_t oWdWH   = oWdecC + 1048576;           // f16 [256][512]  = WdecW
constexpr size_t oEncSt  = oWdWH + 65536;              // f32 [32][512][512]
constexpr size_t oEncPr  = oEncSt + (size_t)kB*kT*kHE; // f32 [32*512][256]
constexpr size_t oHdec   = oEncPr + (size_t)kB*kT*kA;  // f32 [3][32][512]
constexpr size_t oCtx    = oHdec + 3ull*kB*kHD;        // f32 [3][32][512] reduced ctx (x kScale)
constexpr size_t oDen    = oCtx + 3ull*kB*kHE;         // f32 [3][32] reduced denominators
constexpr size_t oScp    = oDen + 96;                  // f32 [32][16][256] dscore partials
constexpr size_t oEbias  = oScp + (size_t)kB*16*kA;    // 2048
constexpr size_t oDbias  = oEbias + 2048;              // 2048
constexpr size_t oAb2    = oDbias + 2048;              // 256
constexpr size_t oCtr    = oAb2 + 256;                 // 2048 ints: [0]=abort, [16]=startgate,
                                                       // [64..575]=slotC, [576..1087]=slotA,
                                                       // [1088..1599]=slotB, [1600..1855]=slotE,
                                                       // [1856..1887]=slotR
constexpr size_t oHenc   = oCtr + 2048;                // f32 [2][32][512] encoder h double buffer
// encst region is DEAD after dec_kernel's start gate (tiles live in registers) -> reuse:
constexpr size_t oCtxP   = oEncSt;                     // f32 [3][32][16][512] ctx partials
constexpr size_t oDenP   = oEncSt + 3ull*32*16*512;    // f32 [3][32][16] denominator partials

constexpr float kScale = 1.0f/64.0f;

DEV float frcp(float x){ return __builtin_amdgcn_rcpf(x); }
DEV float fsig(float x){ return frcp(1.f + __expf(-x)); }
DEV float ftanh(float x){ return 1.f - 2.f*frcp(__expf(2.f*x) + 1.f); }

// relaxed agent-scope (MALL-coherent) accessors
DEV float ld_na(const float* p){ return __hip_atomic_load((float*)p, __ATOMIC_RELAXED, __HIP_MEMORY_SCOPE_AGENT); }
DEV void  st_na(float* p, float v){ __hip_atomic_store(p, v, __ATOMIC_RELAXED, __HIP_MEMORY_SCOPE_AGENT); }
DEV int   ld_ni(const int* p){ return __hip_atomic_load((int*)p, __ATOMIC_RELAXED, __HIP_MEMORY_SCOPE_AGENT); }
DEV void  st_ni(int* p, int v){ __hip_atomic_store(p, v, __ATOMIC_RELAXED, __HIP_MEMORY_SCOPE_AGENT); }
DEV float2 ld_na2(const float* p){
  u64 v = __hip_atomic_load((const u64*)p, __ATOMIC_RELAXED, __HIP_MEMORY_SCOPE_AGENT);
  union { u64 u; float2 f; } cv; cv.u = v; return cv.f;
}
DEV void st_na2(float* p, float2 v){
  union { float2 f; u64 u; } cv; cv.f = v;
  __hip_atomic_store((u64*)p, cv.u, __ATOMIC_RELAXED, __HIP_MEMORY_SCOPE_AGENT);
}

// distributed slot barrier: wave0 sweeps cnt slots with coalesced relaxed loads
DEV void wait_slots(const int* base, int cnt, int tgt, int* abortf){
  if (threadIdx.x < 64){
    int lane = threadIdx.x;
    int guard = 0;
    for (;;){
      int ok = 1;
      for (int i = lane; i < cnt; i += 64) ok &= (ld_ni(base + i) >= tgt);
      if (__all(ok)) break;
      if (ld_ni(abortf) != 0) break;
      if (++guard > (1<<21)){ st_ni(abortf, 1); break; }
      __builtin_amdgcn_s_sleep(1);
    }
  }
  __syncthreads();
}
// single-counter poll (one-time start gate only)
DEV void wait_count(const int* p, int tgt, int* abortf){
  if (threadIdx.x < 64){
    int guard = 0;
    for (;;){
      if (ld_ni(p) >= tgt) break;
      if (ld_ni(abortf) != 0) break;
      if (++guard > (1<<21)){ st_ni(abortf, 1); break; }
      __builtin_amdgcn_s_sleep(2);
    }
  }
  __syncthreads();
}
// arrive: __syncthreads drains each wave's outstanding stores before the stamp issues
DEV void stamp_slot(int* slot, int v){
  __syncthreads();
  if (threadIdx.x == 0) st_ni(slot, v);
}

} // namespace

// ================= kernel 1: init / weight packing =================
__global__ __launch_bounds__(256) void init_kernel(
    const float* __restrict__ eBih, const float* __restrict__ eBhh,
    const float* __restrict__ WdecW, const float* __restrict__ WdecB, const float* __restrict__ attnB,
    const float* __restrict__ dWih, const float* __restrict__ dWhh,
    const float* __restrict__ dBih, const float* __restrict__ dBhh,
    float* __restrict__ ws)
{
  float* whc = ws + oWdecC;            // fp32 [2048][512] = Wih[:,512:] + Whh
  f16* wdwh  = (f16*)(ws + oWdWH);
  float* hdec  = ws + oHdec;
  float* ebias = ws + oEbias;
  float* dbias = ws + oDbias;
  float* ab2w  = ws + oAb2;
  float* henc  = ws + oHenc;
  const int gid = blockIdx.x*256 + threadIdx.x;
  const int stride = gridDim.x*256;
  for (int i=gid; i<2048*512; i+=stride){
    int col = i>>9, k = i&511;
    whc[i] = dWih[((size_t)col<<10) + 512 + k] + dWhh[((size_t)col<<9) + k];
  }
  for (int i=gid; i<256*512; i+=stride)  wdwh[i] = (f16)WdecW[i];
  for (int i=gid; i<2048; i+=stride){ ebias[i] = eBih[i]+eBhh[i]; dbias[i] = dBih[i]+dBhh[i]; }
  for (int i=gid; i<256; i+=stride)  ab2w[i] = WdecB[i]+attnB[i];
  for (int i=gid; i<2*kB*kHE; i+=stride) henc[i] = 0.f;
  for (int i=gid; i<kB*kHD; i+=stride){
    int e = i & 511;
    float zi = dBih[e]+dBhh[e];
    float zg = dBih[1024+e]+dBhh[1024+e];
    float zo = dBih[1536+e]+dBhh[1536+e];
    float c0 = fsig(zi)*ftanh(zg);
    hdec[i] = fsig(zo)*ftanh(c0);   // buffer 0: initial decoder h
  }
}

// ================= kernel 2: encoder — weight-stationary, slot-flag sync =================
__global__ __launch_bounds__(256, 1) void enc_kernel(
    const float* __restrict__ x, const float* __restrict__ eWih,
    const float* __restrict__ eWhh, float* __restrict__ ws)
{
  constexpr int WP = 644;   // w row pad (floats)
  constexpr int XP = 648;   // xh row pad
  __shared__ float wsm[32*WP];
  __shared__ float xh[8*XP];
  __shared__ float zs[8][32];
  const float* ebias = ws + oEbias;
  float* encst = ws + oEncSt;
  float* henc  = ws + oHenc;
  int* ctr = (int*)(ws + oCtr);
  int* abortf = ctr;
  int* slotE = ctr + 1600;

  const int tid = threadIdx.x, bid = blockIdx.x;
  const int q = bid >> 6, j = bid & 63;    // b-group, e-slice
  const int b0 = q*8, e0 = j*8;

  for (int i = tid; i < 32*640; i += 256){
    int r = i / 640, k = i - r*640;
    int gate = r >> 3, el = r & 7;
    int grow = gate*kHE + e0 + el;
    float v = (k < kF) ? eWih[(size_t)grow*kF + k] : eWhh[(size_t)grow*kHE + (k - kF)];
    wsm[r*WP + k] = v;
  }
  const int b_l = tid >> 5, row = tid & 31;       // dot role: (batch, w-row)
  const float biasr = ebias[(row>>3)*kHE + e0 + (row&7)];
  const int b_p = tid >> 3, e_p = tid & 7;        // pointwise role
  float creg = 0.f;
  __syncthreads();

  int p = 0;
  for (int t = 0; t < kT; ++t){
    // stage x_t: each 32-lane half-wave stages its own batch's 128 floats
    {
      int bl2 = tid >> 5, q4 = tid & 31;
      *(float4*)(&xh[bl2*XP + 4*q4]) = ((const float4*)(x + ((size_t)(b0+bl2)*kT + t)*kF))[q4];
    }
    // x-part of the dot BEFORE the h wait (same-wave LDS region -> no barrier;
    // kq order 0..31 then 32..159 into the same accumulators = bit-identical)
    float a0=0.f, a1=0.f, a2=0.f, a3=0.f;
    {
      const float4* wr = (const float4*)(&wsm[row*WP]);
      const float4* xr = (const float4*)(&xh[b_l*XP]);
      #pragma unroll 8
      for (int kq = 0; kq < 32; ++kq){
        float4 w = wr[kq], v = xr[kq];
        a0 += w.x*v.x; a1 += w.y*v.y; a2 += w.z*v.z; a3 += w.w*v.w;
      }
    }
    wait_slots(slotE + q*64, 64, t, abortf);
    // stage h_{t-1} for 8 batches via MALL-coherent 8B loads
    #pragma unroll
    for (int i = 0; i < 4; ++i){
      int idx = tid + 256*i;
      int bl2 = idx >> 7, q4 = idx & 127;
      const float* hsrc = henc + (size_t)p*kB*kHE + (size_t)(b0+bl2)*kHE + 4*q4;
      float2 h01 = ld_na2(hsrc), h23 = ld_na2(hsrc + 2);
      *(float4*)(&xh[bl2*XP + kF + 4*q4]) = make_float4(h01.x, h01.y, h23.x, h23.y);
    }
    __syncthreads();
    {
      const float4* wr = (const float4*)(&wsm[row*WP]);
      const float4* xr = (const float4*)(&xh[b_l*XP]);
      #pragma unroll 8
      for (int kq = 32; kq < 160; ++kq){
        float4 w = wr[kq], v = xr[kq];
        a0 += w.x*v.x; a1 += w.y*v.y; a2 += w.z*v.z; a3 += w.w*v.w;
      }
      zs[b_l][row] = (a0+a1)+(a2+a3) + biasr;
    }
    __syncthreads();
    if (tid < 64){
      float zi = zs[b_p][0*8 + e_p];
      float zf = zs[b_p][1*8 + e_p];
      float zg = zs[b_p][2*8 + e_p];
      float zo = zs[b_p][3*8 + e_p];
      float c2 = fsig(zf)*creg + fsig(zi)*ftanh(zg);
      creg = c2;
      float h = fsig(zo)*ftanh(c2);
      int b = b0 + b_p, e = e0 + e_p;
      st_na(&henc[(size_t)(p^1)*kB*kHE + (size_t)b*kHE + e], h);
      encst[((size_t)b*kT + t)*kHE + e] = h;   // plain; published at kernel end
    }
    stamp_slot(&slotE[q*64 + j], t+1);
    p ^= 1;
  }
}

// ================= kernel 3: enc_proj = enc_states @ Wenc^T + b =================
__global__ __launch_bounds__(256) void encproj_kernel(
    const float* __restrict__ WencW, const float* __restrict__ WencB,
    float* __restrict__ ws)
{
  const float* encst = ws + oEncSt;
  float* encpr = ws + oEncPr;
  __shared__ float4 et[32][32];
  const int tid = threadIdx.x, bid = blockIdx.x;
  const int r0 = bid*32;
  float acc[32];
  #pragma unroll
  for (int i=0;i<32;++i) acc[i]=0.f;
  for (int kt=0; kt<4; ++kt){
    #pragma unroll
    for (int i2=0;i2<4;++i2){
      int q = tid + i2*256;
      int row = q>>5, qi = q&31;
      et[row][qi] = ((const float4*)(encst + ((size_t)(r0+row))*kHE + kt*128))[qi];
    }
    __syncthreads();
    const float4* wv = (const float4*)(WencW + (size_t)tid*kHE + kt*128);
    #pragma unroll 1
    for (int q=0;q<32;++q){
      float4 w = wv[q];
      #pragma unroll
      for (int i=0;i<32;++i){
        float4 e4 = et[i][q];
        acc[i] += e4.x*w.x + e4.y*w.y + e4.z*w.z + e4.w*w.w;
      }
    }
    __syncthreads();
  }
  float bb = WencB[tid];
  #pragma unroll
  for (int i=0;i<32;++i) encpr[((size_t)(r0+i))*kA + tid] = acc[i] + bb;
}

// ================= kernel 4: decoder — R6 flag protocol, fused full-width GEMV rounds =================
// Chain per step: slotC(16) -> A (dscore partial) -> slotA -> B (lw, ctx partial)
// -> slotB -> R (reduce, tc==0 block) -> slotR -> C (ctx-half + pointwise).
// C-prep (full h-half GEMV in ONE LDS round) hoisted before the slotR wait.
namespace {
struct SA  { float h[32]; float sc[256]; float lw[32]; };
struct SC  { float xt[16][520]; float zb[128][2]; };  // xt holds a FULL 512-col row
struct __align__(16) SmemDec {
  float wsl[8][1028];      // fp32 weight slab: rows (gate*2+e_l), K=1024 (ctx|h)
  float v[256];
  SA a;                    // SA live across A/B, SC live across C-prep/C
  SC c;
};
}

__global__ __launch_bounds__(256, 2) void dec_kernel(
    const float* __restrict__ Vw, const float* __restrict__ dWih,
    float* __restrict__ out, float* __restrict__ ws)
{
  __shared__ SmemDec sm;
  const int tid = threadIdx.x, bid = blockIdx.x;
  const float* whc = ws + oWdecC;
  const f16* wdwh  = (const f16*)(ws + oWdWH);
  const float* encst = ws + oEncSt;
  const float* encpr = ws + oEncPr;
  float* hdec = ws + oHdec;
  float* ctxb = ws + oCtx;                        // reduced ctx [3][32][512]
  float* den  = ws + oDen;                        // reduced denom [3][32]
  float* scp  = ws + oScp;
  float* ctxp = ws + oCtxP;                       // partials [3][32][16][512] (aliases encst)
  float* denp = ws + oDenP;                       // partials [3][32][16]
  const float* dbias = ws + oDbias;
  const float* ab2w  = ws + oAb2;
  int* ctr   = (int*)(ws + oCtr);
  int* abortf = ctr;
  int* startc = ctr + 16;
  int* slotC = ctr + 64;     // [2][256] by (half, ecp)
  int* slotA = ctr + 576;    // [32][16] by (b, tc)
  int* slotB = ctr + 1088;   // [32][16] by (b, tc)
  int* slotR = ctr + 1856;   // [32] by b

  const int bA = bid >> 4, tc = bid & 15, t0a = tc*32;      // A/B role
  const int half = bid >> 8, ecp = bid & 255, e0c = ecp*2;  // C role
  const bool isR = (tc == 0);
  const int col_l = tid & 127, ksC = tid >> 7;
  const int e_lC = col_l & 1, gateC = (col_l>>1)&3, b_lC = col_l>>3;
  const int wrow = gateC*2 + e_lC;

  // ---- one-time: weight slab (8 cols x 1024 K) -> LDS
  for (int i = tid; i < 8*1024; i += 256){
    int rr = i >> 10, k = i & 1023;
    int col = (rr>>1)*kHD + e0c + (rr&1);
    float v = (k < 512) ? dWih[(size_t)col*1024 + k] : whc[(size_t)col*512 + (k-512)];
    sm.wsl[rr][k] = v;
  }
  sm.v[tid] = Vw[tid];

  // ---- one-time register residents (step-invariant)
  h4 wA[8];
  { const h4* wv0 = (const h4*)(wdwh + (size_t)tid*kHD + t0a);
    #pragma unroll
    for (int q=0;q<8;++q) wA[q] = wv0[q]; }
  const int tl = tid>>3, as = tid&7;
  float4 eprR[8];
  { const float* eb2 = encpr + ((size_t)bA*kT + t0a + tl)*kA + as*4;
    #pragma unroll
    for (int q=0;q<8;++q) eprR[q] = *(const float4*)(eb2 + q*32); }
  float2 ev[32];                                   // encoder-state tile in regs
  { const float* eb = encst + ((size_t)bA*kT + t0a)*kHE + 2*tid;
    #pragma unroll
    for (int j=0;j<32;++j) ev[j] = *(const float2*)(eb + (size_t)j*kHE); }

  const float ab2r = ab2w[tid];
  float cregD=0, dbi=0, dbf=0, dbg=0, dbo=0;
  if (tid < 32){
    int e = e0c + (tid&1);
    dbi = dbias[e]; dbf = dbias[512+e]; dbg = dbias[1024+e]; dbo = dbias[1536+e];
    cregD = fsig(dbi)*ftanh(dbg);
  }
  // ---- gate: all blocks' encst/encpr register loads complete before alias writes
  __syncthreads();
  if (tid == 0) atomicAdd(startc, 1);
  wait_count(startc, 512, abortf);

  int r = 0;
  for (int t=0; t<kT; ++t){
    const int rn = (r==2) ? 0 : r+1;
    // ---- A: wait h producers (16 slots = 1 line), dscore partial ----
    wait_slots(slotC + (bA>>4)*256 + tc*16, 16, t, abortf);
    if (tid < 32) sm.a.h[tid] = ld_na(hdec + (size_t)r*kB*kHD + (size_t)bA*kHD + t0a + tid);
    __syncthreads();
    {
      float sp = 0.f;
      #pragma unroll
      for (int q=0;q<8;++q){
        h4 w = wA[q];
        sp += (float)w.x*sm.a.h[q*4+0] + (float)w.y*sm.a.h[q*4+1]
            + (float)w.z*sm.a.h[q*4+2] + (float)w.w*sm.a.h[q*4+3];
      }
      st_na(&scp[((size_t)bA*16 + tc)*kA + tid], sp);
    }
    stamp_slot(&slotA[bA*16 + tc], t+1);
    // ---- B: wait 16 dscore partials, gather, tanh-logits, exp, ctx partial ----
    wait_slots(slotA + bA*16, 16, t+1, abortf);
    {
      float sc = ab2r;
      #pragma unroll
      for (int j=0;j<16;++j) sc += ld_na(&scp[((size_t)bA*16 + j)*kA + tid]);
      sm.a.sc[tid] = sc;
    }
    __syncthreads();
    {
      float acc = 0.f;
      #pragma unroll
      for (int q=0;q<8;++q){
        int a0 = q*32 + as*4;
        float4 e4 = eprR[q];
        acc += sm.v[a0+0]*ftanh(e4.x + sm.a.sc[a0+0]);
        acc += sm.v[a0+1]*ftanh(e4.y + sm.a.sc[a0+1]);
        acc += sm.v[a0+2]*ftanh(e4.z + sm.a.sc[a0+2]);
        acc += sm.v[a0+3]*ftanh(e4.w + sm.a.sc[a0+3]);
      }
      acc += __shfl_down(acc, 4, 8);
      acc += __shfl_down(acc, 2, 8);
      acc += __shfl_down(acc, 1, 8);
      if (as == 0) sm.a.lw[tl] = __expf(acc) * kScale;
    }
    __syncthreads();
    {
      float c0=0.f, c1=0.f;
      #pragma unroll
      for (int j=0;j<32;++j){
        float w = sm.a.lw[j];
        c0 += w*ev[j].x; c1 += w*ev[j].y;
      }
      st_na2(&ctxp[(((size_t)r*kB + bA)*16 + tc)*kHE + 2*tid], make_float2(c0, c1));
      if (tid == 0){
        float ds = 0.f;
        #pragma unroll
        for (int j=0;j<32;++j) ds += sm.a.lw[j];
        st_na(&denp[((size_t)r*kB + bA)*16 + tc], ds);
      }
    }
    stamp_slot(&slotB[bA*16 + tc], t+1);
    // ---- R: one block per batch sums the 16 partials ----
    if (isR){
      wait_slots(slotB + bA*16, 16, t+1, abortf);
      {
        const float* pb = ctxp + ((size_t)r*kB + bA)*16*kHE + 2*tid;
        float s0=0.f, s1=0.f;
        #pragma unroll
        for (int j=0;j<16;++j){
          float2 p = ld_na2(pb + (size_t)j*kHE);
          s0 += p.x; s1 += p.y;
        }
        st_na2(&ctxb[((size_t)r*kB + bA)*kHE + 2*tid], make_float2(s0, s1));
        float d = (tid < 16) ? ld_na(&denp[((size_t)r*kB + bA)*16 + tid]) : 0.f;
        d += __shfl_down(d, 8, 16);
        d += __shfl_down(d, 4, 16);
        d += __shfl_down(d, 2, 16);
        d += __shfl_down(d, 1, 16);
        if (tid == 0) st_na(&den[r*kB + bA], d);
      }
      stamp_slot(&slotR[bA], t+1);
    }
    // ---- C-prep: FULL h-half GEMV in one LDS round (overlaps R's reduction) ----
    wait_slots(slotC + half*256, 256, t, abortf);
    float acch = 0.f;
    {
      const float* hbase = hdec + (size_t)r*kB*kHD + (size_t)(half*16)*kHD + 2*tid;
      float2 hu[16];
      #pragma unroll
      for (int b=0;b<16;++b) hu[b] = ld_na2(hbase + (size_t)b*kHD);
      #pragma unroll
      for (int b=0;b<16;++b) *(float2*)(&sm.c.xt[b][2*tid]) = hu[b];
      __syncthreads();
      #pragma unroll
      for (int kc=2; kc<4; ++kc){     // chunk order 2 then 3 = same accumulation order
        const float4* wc4 = (const float4*)(&sm.wsl[wrow][kc*256 + ksC*128]);
        const float4* xv  = (const float4*)(&sm.c.xt[b_lC][(kc-2)*256 + ksC*128]);
        float a0=0.f, a1=0.f, a2=0.f, a3=0.f;
        #pragma unroll 8
        for (int q=0;q<32;++q){
          float4 w = wc4[q], v = xv[q];
          a0 += w.x*v.x; a1 += w.y*v.y; a2 += w.z*v.z; a3 += w.w*v.w;
        }
        acch += (a0+a1)+(a2+a3);
      }
      __syncthreads();
    }
    // ---- C: wait the half's 16 reducers (1 flag line), ctx GEMV in one round ----
    wait_slots(slotR + half*16, 16, t+1, abortf);
    {
      const float rv = frcp(ld_na(&den[r*kB + half*16 + b_lC]));
      const float* cbase = ctxb + (size_t)r*kB*kHE + (size_t)(half*16)*kHE + 2*tid;
      float2 cu[16];
      #pragma unroll
      for (int b=0;b<16;++b) cu[b] = ld_na2(cbase + (size_t)b*kHE);
      #pragma unroll
      for (int b=0;b<16;++b) *(float2*)(&sm.c.xt[b][2*tid]) = cu[b];
      __syncthreads();
      float accc = 0.f;
      #pragma unroll
      for (int kc=0; kc<2; ++kc){     // chunk order 0 then 1 = same accumulation order
        const float4* wc4 = (const float4*)(&sm.wsl[wrow][kc*256 + ksC*128]);
        const float4* xv  = (const float4*)(&sm.c.xt[b_lC][kc*256 + ksC*128]);
        float a0=0.f, a1=0.f, a2=0.f, a3=0.f;
        #pragma unroll 8
        for (int q=0;q<32;++q){
          float4 w = wc4[q], v = xv[q];
          a0 += w.x*v.x; a1 += w.y*v.y; a2 += w.z*v.z; a3 += w.w*v.w;
        }
        accc += (a0+a1)+(a2+a3);
      }
      sm.c.zb[col_l][ksC] = accc*rv + acch;
      __syncthreads();
      if (tid < 32){
        int base = (tid>>1)*8 + (tid&1);
        int e = e0c + (tid&1), b2 = half*16 + (tid>>1);
        float zi = sm.c.zb[base+0][0] + sm.c.zb[base+0][1] + dbi;
        float zf = sm.c.zb[base+2][0] + sm.c.zb[base+2][1] + dbf;
        float zg = sm.c.zb[base+4][0] + sm.c.zb[base+4][1] + dbg;
        float zo = sm.c.zb[base+6][0] + sm.c.zb[base+6][1] + dbo;
        float c2 = fsig(zf)*cregD + fsig(zi)*ftanh(zg);
        cregD = c2;
        float h = fsig(zo)*ftanh(c2);
        st_na(&hdec[(size_t)rn*kB*kHD + (size_t)b2*kHD + e], h);
        out[((size_t)b2*kT + t)*kHD + e] = h;
      }
    }
    stamp_slot(&slotC[half*256 + ecp], t+1);
    r = rn;
  }
}

extern "C" void kernel_launch(void* const* d_in, const int* in_sizes, int n_in,
                              void* d_out, int out_size, void* d_ws, size_t ws_size,
                              hipStream_t stream) {
  (void)in_sizes; (void)n_in; (void)out_size; (void)ws_size; // needs ws >= ~56 MB
  const float* x     = (const float*)d_in[0];
  const float* eWih  = (const float*)d_in[1];
  const float* eWhh  = (const float*)d_in[2];
  const float* eBih  = (const float*)d_in[3];
  const float* eBhh  = (const float*)d_in[4];
  const float* WencW = (const float*)d_in[5];
  const float* WencB = (const float*)d_in[6];
  const float* WdecW = (const float*)d_in[7];
  const float* WdecB = (const float*)d_in[8];
  const float* Vw    = (const float*)d_in[9];
  const float* attnB = (const float*)d_in[11];
  const float* dWih  = (const float*)d_in[12];
  const float* dWhh  = (const float*)d_in[13];
  const float* dBih  = (const float*)d_in[14];
  const float* dBhh  = (const float*)d_in[15];
  float* ws = (float*)d_ws;
  int* ctr = (int*)(ws + oCtr);
  hipMemsetAsync(ctr, 0, 8192, stream);
  hipLaunchKernelGGL(init_kernel, dim3(512), dim3(256), 0, stream,
                     eBih, eBhh, WdecW, WdecB, attnB, dWih, dWhh, dBih, dBhh, ws);
  hipLaunchKernelGGL(enc_kernel, dim3(256), dim3(256), 0, stream, x, eWih, eWhh, ws);
  hipLaunchKernelGGL(encproj_kernel, dim3(512), dim3(256), 0, stream, WencW, WencB, ws);
  hipLaunchKernelGGL(dec_kernel, dim3(512), dim3(256), 0, stream, Vw, dWih, (float*)d_out, ws);
}